// Round 1
// baseline (157.216 us; speedup 1.0000x reference)
//
#include <hip/hip_runtime.h>
#include <math.h>

#define T_SEQ 2048
#define DMODEL 256
#define C_HEAD 64
#define NH 4
#define NWIN 16
#define TB 8

// ---------------- Kernel 1: QKV projection + RMSNorm + RoPE ----------------
// grid = B*T/TB blocks, 384 threads (6 waves). Each wave = one 64-channel norm
// group (Q heads 0..3, K, V). Each thread computes one output column for TB rows.
__global__ __launch_bounds__(384) void qkv_kernel(
    const float* __restrict__ H, const float* __restrict__ WQ,
    const float* __restrict__ WK, const float* __restrict__ WV,
    const float* __restrict__ wq, const float* __restrict__ wk,
    const float* __restrict__ wv,
    float* __restrict__ Qb, float* __restrict__ Kb, float* __restrict__ Vb)
{
    __shared__ __align__(16) float hrow[TB][DMODEL];
    const int tid = threadIdx.x;
    const long row0 = (long)blockIdx.x * TB;
    const int b = (int)(row0 / T_SEQ);
    const int t0 = (int)(row0 % T_SEQ);

    // stage TB H-rows into LDS
    const float* hsrc = H + row0 * DMODEL;
    for (int i = tid; i < TB * DMODEL; i += 384)
        ((float*)hrow)[i] = hsrc[i];
    __syncthreads();

    const int j = tid;
    const float* w;
    if (j < 256)       w = WQ + j * DMODEL;
    else if (j < 320)  w = WK + (j - 256) * DMODEL;
    else               w = WV + (j - 320) * DMODEL;

    float acc[TB];
    #pragma unroll
    for (int r = 0; r < TB; ++r) acc[r] = 0.f;

    const float4* w4 = (const float4*)w;
    #pragma unroll 8
    for (int i = 0; i < DMODEL / 4; ++i) {
        float4 wv4 = w4[i];
        #pragma unroll
        for (int r = 0; r < TB; ++r) {
            float4 h4 = ((const float4*)hrow[r])[i];
            acc[r] += h4.x * wv4.x + h4.y * wv4.y + h4.z * wv4.z + h4.w * wv4.w;
        }
    }

    const int g = tid >> 6;   // wave index 0..5 = norm group
    const int m = tid & 63;   // channel within group
    float gw;
    if (g < 4)       gw = wq[g * C_HEAD + m];
    else if (g == 4) gw = wk[m];
    else             gw = wv[m];

    const int kk = (m - 48) >> 1;
    const float th = (m >= 48) ? powf(10000.0f, -0.125f * (float)kk) : 0.f;

    #pragma unroll
    for (int r = 0; r < TB; ++r) {
        float v = acc[r];
        float ss = v * v;
        #pragma unroll
        for (int off = 32; off >= 1; off >>= 1) ss += __shfl_xor(ss, off);
        float x = v * rsqrtf(ss * (1.0f / C_HEAD) + 1e-8f) * gw;
        float px = __shfl_xor(x, 1);   // rope pair partner (all lanes execute)
        const int t = t0 + r;
        if (m >= 48) {
            float fr = (float)t * th;
            float cv = cosf(fr), sv = sinf(fr);
            if ((m & 1) == 0) x = x * cv - px * sv;   // rx1 = x1*cos - x2*sin
            else              x = px * sv + x * cv;   // rx2 = x1*sin + x2*cos
        }
        if (g < 4)       Qb[(((long)(b * NH + g) * T_SEQ + t) * C_HEAD) + m] = x;
        else if (g == 4) Kb[(((long)b * T_SEQ + t) * C_HEAD) + m] = x;
        else             Vb[(((long)b * T_SEQ + t) * C_HEAD) + m] = x;
    }
}

// ---------------- Kernel 2: sliding-window attention + inverse RoPE --------
// one wave per (b,h,t); lane = channel. 16 keys fully unrolled.
__global__ __launch_bounds__(256) void attn_kernel(
    const float* __restrict__ Qb, const float* __restrict__ Kb,
    const float* __restrict__ Vb, float* __restrict__ Ob)
{
    const int tid = threadIdx.x;
    const int lane = tid & 63;
    const int w = blockIdx.x * 4 + (tid >> 6);
    const int t = w & (T_SEQ - 1);
    const int h = (w >> 11) & (NH - 1);
    const int b = w >> 13;

    const float q = Qb[(((long)(b * NH + h) * T_SEQ + t) * C_HEAD) + lane];
    const float* Kbase = Kb + (long)b * T_SEQ * C_HEAD;
    const float* Vbase = Vb + (long)b * T_SEQ * C_HEAD;

    float s[NWIN];
    float mx = -1e30f;
    #pragma unroll
    for (int idx = 0; idx < NWIN; ++idx) {
        const int jj = t - (NWIN - 1) + idx;     // uniform across wave
        float kv = (jj >= 0) ? Kbase[(long)jj * C_HEAD + lane] : 0.f;
        float p = q * kv;
        #pragma unroll
        for (int off = 32; off >= 1; off >>= 1) p += __shfl_xor(p, off);
        s[idx] = (jj >= 0) ? p * 0.125f : -1e30f;
        mx = fmaxf(mx, s[idx]);
    }
    float sum = 0.f;
    #pragma unroll
    for (int idx = 0; idx < NWIN; ++idx) {
        s[idx] = expf(s[idx] - mx);
        sum += s[idx];
    }
    float o = 0.f;
    #pragma unroll
    for (int idx = 0; idx < NWIN; ++idx) {
        const int jj = t - (NWIN - 1) + idx;
        if (jj >= 0) o += s[idx] * Vbase[(long)jj * C_HEAD + lane];
    }
    o /= sum;

    // inverse rope (t -> -t): cos same, sin negated
    float po = __shfl_xor(o, 1);
    if (lane >= 48) {
        const int kk = (lane - 48) >> 1;
        float th = powf(10000.0f, -0.125f * (float)kk);
        float fr = (float)t * th;
        float cv = cosf(fr), sv = sinf(fr);
        if ((lane & 1) == 0) o =  o * cv + po * sv;   // x1*cos + x2*sin
        else                 o = -po * sv + o * cv;   // -x1*sin + x2*cos
    }
    Ob[(((long)b * T_SEQ + t) * DMODEL) + h * C_HEAD + lane] = o;
}

// ---------------- Kernel 3: gate projections + output projection ----------
__global__ __launch_bounds__(256) void out_kernel(
    const float* __restrict__ Ob, const float* __restrict__ Wg0,
    const float* __restrict__ bg0, const float* __restrict__ Wg1,
    const float* __restrict__ bg1, const float* __restrict__ Wout,
    const float* __restrict__ bout, float* __restrict__ out)
{
    __shared__ __align__(16) float orow[TB][DMODEL];
    __shared__ __align__(16) float prow[TB][128];
    const int tid = threadIdx.x;
    const long row0 = (long)blockIdx.x * TB;

    const float* osrc = Ob + row0 * DMODEL;
    for (int i = tid; i < TB * DMODEL; i += 256)
        ((float*)orow)[i] = osrc[i];
    __syncthreads();

    if (tid < 128) {
        const int jj = tid & 63;
        const float* Wg = (tid < 64) ? (Wg0 + jj * 128) : (Wg1 + jj * 128);
        const float  bb = (tid < 64) ? bg0[jj] : bg1[jj];
        const int ofs4 = (tid < 64) ? 0 : 32;   // float4 offset into O row
        float acc[TB];
        #pragma unroll
        for (int r = 0; r < TB; ++r) acc[r] = 0.f;
        const float4* wg4 = (const float4*)Wg;
        #pragma unroll 4
        for (int i = 0; i < 32; ++i) {
            float4 w4 = wg4[i];
            #pragma unroll
            for (int r = 0; r < TB; ++r) {
                float4 o4 = ((const float4*)orow[r])[ofs4 + i];
                acc[r] += o4.x * w4.x + o4.y * w4.y + o4.z * w4.z + o4.w * w4.w;
            }
        }
        #pragma unroll
        for (int r = 0; r < TB; ++r) prow[r][tid] = acc[r] + bb;
    }
    __syncthreads();
    {
        float acc[TB];
        #pragma unroll
        for (int r = 0; r < TB; ++r) acc[r] = 0.f;
        const float4* wo4 = (const float4*)(Wout + tid * 128);
        #pragma unroll 4
        for (int i = 0; i < 32; ++i) {
            float4 w4 = wo4[i];
            #pragma unroll
            for (int r = 0; r < TB; ++r) {
                float4 p4 = ((const float4*)prow[r])[i];
                acc[r] += p4.x * w4.x + p4.y * w4.y + p4.z * w4.z + p4.w * w4.w;
            }
        }
        const float bb = bout[tid];
        #pragma unroll
        for (int r = 0; r < TB; ++r)
            out[(row0 + r) * DMODEL + tid] = acc[r] + bb;
    }
}

extern "C" void kernel_launch(void* const* d_in, const int* in_sizes, int n_in,
                              void* d_out, int out_size, void* d_ws, size_t ws_size,
                              hipStream_t stream) {
    const float* H    = (const float*)d_in[0];
    const float* WQ   = (const float*)d_in[1];
    const float* WK   = (const float*)d_in[2];
    const float* WV   = (const float*)d_in[3];
    const float* wq   = (const float*)d_in[4];
    const float* wk   = (const float*)d_in[5];
    const float* wv   = (const float*)d_in[6];
    const float* Wg0  = (const float*)d_in[7];
    const float* bg0  = (const float*)d_in[8];
    const float* Wg1  = (const float*)d_in[9];
    const float* bg1  = (const float*)d_in[10];
    const float* Wout = (const float*)d_in[11];
    const float* bout = (const float*)d_in[12];
    float* out = (float*)d_out;

    const int B = 4;
    float* ws = (float*)d_ws;
    float* Qb = ws;                       // B*NH*T*C = 2097152 floats
    float* Kb = Qb + (long)B * NH * T_SEQ * C_HEAD;   // 524288
    float* Vb = Kb + (long)B * T_SEQ * C_HEAD;        // 524288
    float* Ob = Vb + (long)B * T_SEQ * C_HEAD;        // 2097152

    qkv_kernel<<<B * T_SEQ / TB, 384, 0, stream>>>(H, WQ, WK, WV, wq, wk, wv, Qb, Kb, Vb);
    attn_kernel<<<B * NH * T_SEQ / 4, 256, 0, stream>>>(Qb, Kb, Vb, Ob);
    out_kernel<<<B * T_SEQ / TB, 256, 0, stream>>>(Ob, Wg0, bg0, Wg1, bg1, Wout, bout, out);
}

// Round 2
// 94.653 us; speedup vs baseline: 1.6610x; 1.6610x over previous
//
#include <hip/hip_runtime.h>
#include <math.h>

#define T_SEQ 2048
#define DMODEL 256
#define C_HEAD 64
#define NH 4
#define NWIN 16
#define B_SZ 4

typedef __attribute__((ext_vector_type(8))) short bf16x8;
typedef __attribute__((ext_vector_type(8))) unsigned short ushort8;
typedef __attribute__((ext_vector_type(4))) float f32x4;

static __device__ __forceinline__ unsigned short f2bf(float f) {
    union { float f; unsigned int u; } v; v.f = f;
    unsigned int r = v.u + 0x7FFFu + ((v.u >> 16) & 1u);
    return (unsigned short)(r >> 16);
}

// ---------------- convert H (f32 -> bf16), 2097152 elems ----------------
__global__ __launch_bounds__(256) void conv_h_kernel(const float* __restrict__ src,
                                                     unsigned short* __restrict__ dst) {
    const int i = blockIdx.x * 256 + threadIdx.x;       // 262144 vec8
    const float4* s4 = (const float4*)src + (size_t)i * 2;
    float4 a = s4[0], b = s4[1];
    ushort8 o;
    o[0] = f2bf(a.x); o[1] = f2bf(a.y); o[2] = f2bf(a.z); o[3] = f2bf(a.w);
    o[4] = f2bf(b.x); o[5] = f2bf(b.y); o[6] = f2bf(b.z); o[7] = f2bf(b.w);
    *(ushort8*)(dst + (size_t)i * 8) = o;
}

// ---------------- convert all weights into one packed bf16 region -------
// layout (elems): WQ[0,65536) WK[65536,81920) WV[81920,98304)
//                 Wg0[98304,106496) Wg1[106496,114688) Wout[114688,147456)
__global__ __launch_bounds__(256) void conv_w_kernel(
    const float* __restrict__ WQ, const float* __restrict__ WK,
    const float* __restrict__ WV, const float* __restrict__ Wg0,
    const float* __restrict__ Wg1, const float* __restrict__ Wout,
    unsigned short* __restrict__ dst) {
    const int i = blockIdx.x * 256 + threadIdx.x;       // 18432 vec8
    const long e = (long)i * 8;
    const float* s; long off;
    if      (e < 65536)  { s = WQ;   off = e; }
    else if (e < 81920)  { s = WK;   off = e - 65536; }
    else if (e < 98304)  { s = WV;   off = e - 81920; }
    else if (e < 106496) { s = Wg0;  off = e - 98304; }
    else if (e < 114688) { s = Wg1;  off = e - 106496; }
    else                 { s = Wout; off = e - 114688; }
    const float4* s4 = (const float4*)(s + off);
    float4 a = s4[0], b = s4[1];
    ushort8 o;
    o[0] = f2bf(a.x); o[1] = f2bf(a.y); o[2] = f2bf(a.z); o[3] = f2bf(a.w);
    o[4] = f2bf(b.x); o[5] = f2bf(b.y); o[6] = f2bf(b.z); o[7] = f2bf(b.w);
    *(ushort8*)(dst + e) = o;
}

// ---------------- Kernel 1: MFMA QKV projection + RMSNorm + RoPE --------
// grid = 8192/32 = 256 blocks, 384 thr (6 waves). Wave g = output col group
// g*64..g*64+63 (Q heads 0..3, K, V). M-tile = 32 tokens. K = 256 in one shot.
__global__ __launch_bounds__(384) void qkv_mfma_kernel(
    const unsigned short* __restrict__ Hb, const unsigned short* __restrict__ Wb,
    const float* __restrict__ wq, const float* __restrict__ wk,
    const float* __restrict__ wv,
    float* __restrict__ Qb, float* __restrict__ Kb, float* __restrict__ Vb)
{
    __shared__ __align__(16) unsigned short lds_a[32 * 256];   // 16KB, swizzled
    const int tid = threadIdx.x;
    const int row0 = blockIdx.x * 32;
    const int b = row0 >> 11;
    const int tbase = row0 & (T_SEQ - 1);

    // stage A tile (32 x 256 bf16) with st-swizzle: byte ^= (row&7)<<4
    {
        const unsigned short* hsrc = Hb + (size_t)row0 * DMODEL;
        for (int idx = tid; idx < 1024; idx += 384) {
            int row = idx >> 5, ch = idx & 31;
            int byte = row * 512 + ch * 16;
            byte ^= (row & 7) << 4;
            *(ushort8*)((char*)lds_a + byte) = *(const ushort8*)(hsrc + row * 256 + ch * 8);
        }
    }
    __syncthreads();

    const int g = tid >> 6;        // wave = col group
    const int l = tid & 63;
    const int q = l >> 4, li = l & 15;

    f32x4 acc[2][4] = {};
    #pragma unroll
    for (int ks = 0; ks < 8; ++ks) {
        const int k0 = ks * 32;
        bf16x8 a[2];
        #pragma unroll
        for (int mf = 0; mf < 2; ++mf) {
            int row = mf * 16 + li;
            int byte = row * 512 + (k0 + q * 8) * 2;
            byte ^= (row & 7) << 4;
            a[mf] = *(const bf16x8*)((const char*)lds_a + byte);
        }
        #pragma unroll
        for (int nf = 0; nf < 4; ++nf) {
            const int col = g * 64 + nf * 16 + li;
            bf16x8 bfr = *(const bf16x8*)(Wb + (size_t)col * 256 + k0 + q * 8);
            acc[0][nf] = __builtin_amdgcn_mfma_f32_16x16x32_bf16(a[0], bfr, acc[0][nf], 0, 0, 0);
            acc[1][nf] = __builtin_amdgcn_mfma_f32_16x16x32_bf16(a[1], bfr, acc[1][nf], 0, 0, 0);
        }
    }

    // epilogue: rmsnorm (per row over 64 cols) + rope on cols 48..63
    float gw[4];
    #pragma unroll
    for (int nf = 0; nf < 4; ++nf) {
        const int c = nf * 16 + li;
        gw[nf] = (g < 4) ? wq[g * 64 + c] : (g == 4 ? wk[c] : wv[c]);
    }
    const float th = powf(10000.0f, -0.125f * (float)(li >> 1));

    float* dstbase;
    if (g < 4)       dstbase = Qb + ((size_t)(b * NH + g) * T_SEQ) * C_HEAD;
    else if (g == 4) dstbase = Kb + ((size_t)b * T_SEQ) * C_HEAD;
    else             dstbase = Vb + ((size_t)b * T_SEQ) * C_HEAD;

    #pragma unroll
    for (int mf = 0; mf < 2; ++mf) {
        #pragma unroll
        for (int r = 0; r < 4; ++r) {
            float x0 = acc[mf][0][r], x1 = acc[mf][1][r];
            float x2 = acc[mf][2][r], x3 = acc[mf][3][r];
            float ss = x0 * x0 + x1 * x1 + x2 * x2 + x3 * x3;
            ss += __shfl_xor(ss, 1);
            ss += __shfl_xor(ss, 2);
            ss += __shfl_xor(ss, 4);
            ss += __shfl_xor(ss, 8);
            const float rinv = rsqrtf(ss * (1.0f / 64.0f) + 1e-8f);
            const int t = tbase + mf * 16 + q * 4 + r;
            float v0 = x0 * rinv * gw[0];
            float v1 = x1 * rinv * gw[1];
            float v2 = x2 * rinv * gw[2];
            float v3 = x3 * rinv * gw[3];
            // rope on cols 48..63 (nf==3): pair partner = lane^1
            float px = __shfl_xor(v3, 1);
            float fr = (float)t * th;
            float cv = cosf(fr), sv = sinf(fr);
            v3 = ((li & 1) == 0) ? (v3 * cv - px * sv) : (px * sv + v3 * cv);
            float* d = dstbase + (size_t)t * C_HEAD;
            d[0 * 16 + li] = v0;
            d[1 * 16 + li] = v1;
            d[2 * 16 + li] = v2;
            d[3 * 16 + li] = v3;
        }
    }
}

// ---------------- Kernel 2: sliding-window attention + inverse RoPE -----
__global__ __launch_bounds__(256) void attn_kernel(
    const float* __restrict__ Qb, const float* __restrict__ Kb,
    const float* __restrict__ Vb, unsigned short* __restrict__ Obh)
{
    const int tid = threadIdx.x;
    const int lane = tid & 63;
    const int w = blockIdx.x * 4 + (tid >> 6);
    const int t = w & (T_SEQ - 1);
    const int h = (w >> 11) & (NH - 1);
    const int b = w >> 13;

    const float q = Qb[(((size_t)(b * NH + h) * T_SEQ + t) * C_HEAD) + lane];
    const float* Kbase = Kb + (size_t)b * T_SEQ * C_HEAD;
    const float* Vbase = Vb + (size_t)b * T_SEQ * C_HEAD;

    float s[NWIN];
    float mx = -1e30f;
    #pragma unroll
    for (int idx = 0; idx < NWIN; ++idx) {
        const int jj = t - (NWIN - 1) + idx;
        float kv = (jj >= 0) ? Kbase[(size_t)jj * C_HEAD + lane] : 0.f;
        float p = q * kv;
        #pragma unroll
        for (int off = 32; off >= 1; off >>= 1) p += __shfl_xor(p, off);
        s[idx] = (jj >= 0) ? p * 0.125f : -1e30f;
        mx = fmaxf(mx, s[idx]);
    }
    float sum = 0.f;
    #pragma unroll
    for (int idx = 0; idx < NWIN; ++idx) {
        s[idx] = expf(s[idx] - mx);
        sum += s[idx];
    }
    float o = 0.f;
    #pragma unroll
    for (int idx = 0; idx < NWIN; ++idx) {
        const int jj = t - (NWIN - 1) + idx;
        if (jj >= 0) o += s[idx] * Vbase[(size_t)jj * C_HEAD + lane];
    }
    o /= sum;

    float po = __shfl_xor(o, 1);
    if (lane >= 48) {
        const int kk = (lane - 48) >> 1;
        float th = powf(10000.0f, -0.125f * (float)kk);
        float fr = (float)t * th;
        float cv = cosf(fr), sv = sinf(fr);
        if ((lane & 1) == 0) o =  o * cv + po * sv;
        else                 o = -po * sv + o * cv;
    }
    Obh[(((size_t)b * T_SEQ + t) * DMODEL) + h * C_HEAD + lane] = f2bf(o);
}

// ---------------- Kernel 3: fused gates + output projection (MFMA) ------
// grid = 256 blocks, 256 thr (4 waves). M-tile = 32 tokens.
// phase1: p[32x128] (wave w: gate=w>>1, p-cols w*32..w*32+31), phase2: out[32x256].
__global__ __launch_bounds__(256) void out_mfma_kernel(
    const unsigned short* __restrict__ Obh, const unsigned short* __restrict__ Wallb,
    const float* __restrict__ bg0, const float* __restrict__ bg1,
    const float* __restrict__ bout, float* __restrict__ out)
{
    __shared__ __align__(16) unsigned short o_tile[32 * 256];  // 16KB, swizzled
    __shared__ __align__(16) unsigned short p_tile[32 * 128];  // 8KB, swizzled
    const int tid = threadIdx.x;
    const int row0 = blockIdx.x * 32;
    const unsigned short* Wg0b  = Wallb + 98304;
    const unsigned short* Wg1b  = Wallb + 106496;
    const unsigned short* Woutb = Wallb + 114688;

    {
        const unsigned short* osrc = Obh + (size_t)row0 * DMODEL;
        for (int idx = tid; idx < 1024; idx += 256) {
            int row = idx >> 5, ch = idx & 31;
            int byte = row * 512 + ch * 16;
            byte ^= (row & 7) << 4;
            *(ushort8*)((char*)o_tile + byte) = *(const ushort8*)(osrc + row * 256 + ch * 8);
        }
    }
    __syncthreads();

    const int w = tid >> 6;
    const int l = tid & 63;
    const int q = l >> 4, li = l & 15;
    const int gate = w >> 1, half = w & 1;
    const unsigned short* Wgb = gate ? Wg1b : Wg0b;
    const float* bg = gate ? bg1 : bg0;

    // phase 1: p-cols (within gate) = half*32 + nf*16 + li, K = O cols gate*128..+127
    {
        f32x4 accp[2][2] = {};
        #pragma unroll
        for (int ks = 0; ks < 4; ++ks) {
            const int k0 = ks * 32;
            bf16x8 a[2];
            #pragma unroll
            for (int mf = 0; mf < 2; ++mf) {
                int row = mf * 16 + li;
                int byte = row * 512 + (gate * 128 + k0 + q * 8) * 2;
                byte ^= (row & 7) << 4;
                a[mf] = *(const bf16x8*)((const char*)o_tile + byte);
            }
            #pragma unroll
            for (int nf = 0; nf < 2; ++nf) {
                const int cl = half * 32 + nf * 16 + li;   // col within gate [0,64)
                bf16x8 bfr = *(const bf16x8*)(Wgb + (size_t)cl * 128 + k0 + q * 8);
                accp[0][nf] = __builtin_amdgcn_mfma_f32_16x16x32_bf16(a[0], bfr, accp[0][nf], 0, 0, 0);
                accp[1][nf] = __builtin_amdgcn_mfma_f32_16x16x32_bf16(a[1], bfr, accp[1][nf], 0, 0, 0);
            }
        }
        // write p tile (bias + bf16) swizzled
        #pragma unroll
        for (int nf = 0; nf < 2; ++nf) {
            const int cl = half * 32 + nf * 16 + li;
            const int pcol = gate * 64 + cl;               // [0,128)
            const float bb = bg[cl];
            #pragma unroll
            for (int mf = 0; mf < 2; ++mf) {
                #pragma unroll
                for (int r = 0; r < 4; ++r) {
                    int row = mf * 16 + q * 4 + r;
                    int byte = row * 256 + pcol * 2;
                    byte ^= (row & 7) << 4;
                    *(unsigned short*)((char*)p_tile + byte) = f2bf(accp[mf][nf][r] + bb);
                }
            }
        }
    }
    __syncthreads();

    // phase 2: out cols = w*64 + nf*16 + li, K = 128 (p_tile)
    {
        f32x4 acco[2][4] = {};
        #pragma unroll
        for (int ks = 0; ks < 4; ++ks) {
            const int k0 = ks * 32;
            bf16x8 a[2];
            #pragma unroll
            for (int mf = 0; mf < 2; ++mf) {
                int row = mf * 16 + li;
                int byte = row * 256 + (k0 + q * 8) * 2;
                byte ^= (row & 7) << 4;
                a[mf] = *(const bf16x8*)((const char*)p_tile + byte);
            }
            #pragma unroll
            for (int nf = 0; nf < 4; ++nf) {
                const int col = w * 64 + nf * 16 + li;
                bf16x8 bfr = *(const bf16x8*)(Woutb + (size_t)col * 128 + k0 + q * 8);
                acco[0][nf] = __builtin_amdgcn_mfma_f32_16x16x32_bf16(a[0], bfr, acco[0][nf], 0, 0, 0);
                acco[1][nf] = __builtin_amdgcn_mfma_f32_16x16x32_bf16(a[1], bfr, acco[1][nf], 0, 0, 0);
            }
        }
        #pragma unroll
        for (int nf = 0; nf < 4; ++nf) {
            const int col = w * 64 + nf * 16 + li;
            const float bb = bout[col];
            #pragma unroll
            for (int mf = 0; mf < 2; ++mf) {
                #pragma unroll
                for (int r = 0; r < 4; ++r) {
                    const int row = mf * 16 + q * 4 + r;
                    out[(size_t)(row0 + row) * DMODEL + col] = acco[mf][nf][r] + bb;
                }
            }
        }
    }
}

extern "C" void kernel_launch(void* const* d_in, const int* in_sizes, int n_in,
                              void* d_out, int out_size, void* d_ws, size_t ws_size,
                              hipStream_t stream) {
    const float* H    = (const float*)d_in[0];
    const float* WQ   = (const float*)d_in[1];
    const float* WK   = (const float*)d_in[2];
    const float* WV   = (const float*)d_in[3];
    const float* wq   = (const float*)d_in[4];
    const float* wk   = (const float*)d_in[5];
    const float* wv   = (const float*)d_in[6];
    const float* Wg0  = (const float*)d_in[7];
    const float* bg0  = (const float*)d_in[8];
    const float* Wg1  = (const float*)d_in[9];
    const float* bg1  = (const float*)d_in[10];
    const float* Wout = (const float*)d_in[11];
    const float* bout = (const float*)d_in[12];
    float* out = (float*)d_out;

    char* ws = (char*)d_ws;
    unsigned short* Hb    = (unsigned short*)ws;                    // 4,194,304 B
    unsigned short* Wallb = (unsigned short*)(ws + 4194304);        //   294,912 B
    float* Qb = (float*)(ws + 4489216);                             // 8,388,608 B
    float* Kb = (float*)(ws + 12877824);                            // 2,097,152 B
    float* Vb = (float*)(ws + 14974976);                            // 2,097,152 B
    unsigned short* Obh = (unsigned short*)(ws + 17072128);         // 4,194,304 B

    conv_h_kernel<<<1024, 256, 0, stream>>>(H, Hb);
    conv_w_kernel<<<72, 256, 0, stream>>>(WQ, WK, WV, Wg0, Wg1, Wout, Wallb);
    qkv_mfma_kernel<<<256, 384, 0, stream>>>(Hb, Wallb, wq, wk, wv, Qb, Kb, Vb);
    attn_kernel<<<B_SZ * NH * T_SEQ / 4, 256, 0, stream>>>(Qb, Kb, Vb, Obh);
    out_mfma_kernel<<<256, 256, 0, stream>>>(Obh, Wallb, bg0, bg1, bout, out);
}

// Round 4
// 42.653 us; speedup vs baseline: 3.6859x; 2.2191x over previous
//
#include <hip/hip_runtime.h>
#include <math.h>

#define T_SEQ 2048
#define DMODEL 256
#define C_HEAD 64
#define NH 4
#define NWIN 16
#define B_SZ 4

typedef __attribute__((ext_vector_type(8))) short bf16x8;
typedef __attribute__((ext_vector_type(8))) unsigned short ushort8;
typedef __attribute__((ext_vector_type(4))) float f32x4;

static __device__ __forceinline__ unsigned short f2bf(float f) {
    union { float f; unsigned int u; } v; v.f = f;
    unsigned int r = v.u + 0x7FFFu + ((v.u >> 16) & 1u);
    return (unsigned short)(r >> 16);
}

// ---------------- convert H (f32 -> bf16), 2097152 elems ----------------
__global__ __launch_bounds__(256) void conv_h_kernel(const float* __restrict__ src,
                                                     unsigned short* __restrict__ dst) {
    const int i = blockIdx.x * 256 + threadIdx.x;       // 262144 vec8
    const float4* s4 = (const float4*)src + (size_t)i * 2;
    float4 a = s4[0], b = s4[1];
    ushort8 o;
    o[0] = f2bf(a.x); o[1] = f2bf(a.y); o[2] = f2bf(a.z); o[3] = f2bf(a.w);
    o[4] = f2bf(b.x); o[5] = f2bf(b.y); o[6] = f2bf(b.z); o[7] = f2bf(b.w);
    *(ushort8*)(dst + (size_t)i * 8) = o;
}

// ---------------- convert all weights into one packed bf16 region -------
// layout (elems): WQ[0,65536) WK[65536,81920) WV[81920,98304)
//                 Wg0[98304,106496) Wg1[106496,114688) Wout[114688,147456)
// extra block 72 zeroes the K/V pad rows.
__global__ __launch_bounds__(256) void conv_w_kernel(
    const float* __restrict__ WQ, const float* __restrict__ WK,
    const float* __restrict__ WV, const float* __restrict__ Wg0,
    const float* __restrict__ Wg1, const float* __restrict__ Wout,
    unsigned short* __restrict__ dst,
    unsigned short* __restrict__ kpad, unsigned short* __restrict__ vpad) {
    const int tid = threadIdx.x;
    if (blockIdx.x == 72) {
        ushort8 z = {0, 0, 0, 0, 0, 0, 0, 0};
        if (tid < 128) *(ushort8*)(kpad + tid * 8) = z;
        else           *(ushort8*)(vpad + (tid - 128) * 8) = z;
        return;
    }
    const int i = blockIdx.x * 256 + tid;               // 18432 vec8
    const long e = (long)i * 8;
    const float* s; long off;
    if      (e < 65536)  { s = WQ;   off = e; }
    else if (e < 81920)  { s = WK;   off = e - 65536; }
    else if (e < 98304)  { s = WV;   off = e - 81920; }
    else if (e < 106496) { s = Wg0;  off = e - 98304; }
    else if (e < 114688) { s = Wg1;  off = e - 106496; }
    else                 { s = Wout; off = e - 114688; }
    const float4* s4 = (const float4*)(s + off);
    float4 a = s4[0], b = s4[1];
    ushort8 o;
    o[0] = f2bf(a.x); o[1] = f2bf(a.y); o[2] = f2bf(a.z); o[3] = f2bf(a.w);
    o[4] = f2bf(b.x); o[5] = f2bf(b.y); o[6] = f2bf(b.z); o[7] = f2bf(b.w);
    *(ushort8*)(dst + e) = o;
}

// ---------------- Kernel 1: MFMA QKV projection + RMSNorm + RoPE --------
// grid = 8192/32 = 256 blocks, 384 thr (6 waves). Wave g = output col group
// g*64..g*64+63 (Q heads 0..3, K, V). M-tile = 32 tokens. Outputs bf16.
__global__ __launch_bounds__(384) void qkv_mfma_kernel(
    const unsigned short* __restrict__ Hb, const unsigned short* __restrict__ Wb,
    const float* __restrict__ wq, const float* __restrict__ wk,
    const float* __restrict__ wv,
    unsigned short* __restrict__ Qb, unsigned short* __restrict__ Kb,
    unsigned short* __restrict__ Vb)
{
    __shared__ __align__(16) unsigned short lds_a[32 * 256];   // 16KB, swizzled
    const int tid = threadIdx.x;
    const int row0 = blockIdx.x * 32;
    const int b = row0 >> 11;
    const int tbase = row0 & (T_SEQ - 1);

    {
        const unsigned short* hsrc = Hb + (size_t)row0 * DMODEL;
        for (int idx = tid; idx < 1024; idx += 384) {
            int row = idx >> 5, ch = idx & 31;
            int byte = row * 512 + ch * 16;
            byte ^= (row & 7) << 4;
            *(ushort8*)((char*)lds_a + byte) = *(const ushort8*)(hsrc + row * 256 + ch * 8);
        }
    }
    __syncthreads();

    const int g = tid >> 6;
    const int l = tid & 63;
    const int q = l >> 4, li = l & 15;

    f32x4 acc[2][4] = {};
    #pragma unroll
    for (int ks = 0; ks < 8; ++ks) {
        const int k0 = ks * 32;
        bf16x8 a[2];
        #pragma unroll
        for (int mf = 0; mf < 2; ++mf) {
            int row = mf * 16 + li;
            int byte = row * 512 + (k0 + q * 8) * 2;
            byte ^= (row & 7) << 4;
            a[mf] = *(const bf16x8*)((const char*)lds_a + byte);
        }
        #pragma unroll
        for (int nf = 0; nf < 4; ++nf) {
            const int col = g * 64 + nf * 16 + li;
            bf16x8 bfr = *(const bf16x8*)(Wb + (size_t)col * 256 + k0 + q * 8);
            acc[0][nf] = __builtin_amdgcn_mfma_f32_16x16x32_bf16(a[0], bfr, acc[0][nf], 0, 0, 0);
            acc[1][nf] = __builtin_amdgcn_mfma_f32_16x16x32_bf16(a[1], bfr, acc[1][nf], 0, 0, 0);
        }
    }

    float gw[4];
    #pragma unroll
    for (int nf = 0; nf < 4; ++nf) {
        const int c = nf * 16 + li;
        gw[nf] = (g < 4) ? wq[g * 64 + c] : (g == 4 ? wk[c] : wv[c]);
    }
    const float th = powf(10000.0f, -0.125f * (float)(li >> 1));

    unsigned short* dstbase;
    if (g < 4)       dstbase = Qb + ((size_t)(b * NH + g) * T_SEQ) * C_HEAD;
    else if (g == 4) dstbase = Kb + ((size_t)b * T_SEQ) * C_HEAD;
    else             dstbase = Vb + ((size_t)b * T_SEQ) * C_HEAD;

    #pragma unroll
    for (int mf = 0; mf < 2; ++mf) {
        #pragma unroll
        for (int r = 0; r < 4; ++r) {
            float x0 = acc[mf][0][r], x1 = acc[mf][1][r];
            float x2 = acc[mf][2][r], x3 = acc[mf][3][r];
            float ss = x0 * x0 + x1 * x1 + x2 * x2 + x3 * x3;
            ss += __shfl_xor(ss, 1);
            ss += __shfl_xor(ss, 2);
            ss += __shfl_xor(ss, 4);
            ss += __shfl_xor(ss, 8);
            const float rinv = rsqrtf(ss * (1.0f / 64.0f) + 1e-8f);
            const int t = tbase + mf * 16 + q * 4 + r;
            float v0 = x0 * rinv * gw[0];
            float v1 = x1 * rinv * gw[1];
            float v2 = x2 * rinv * gw[2];
            float v3 = x3 * rinv * gw[3];
            float px = __shfl_xor(v3, 1);
            float fr = (float)t * th;
            float cv = cosf(fr), sv = sinf(fr);
            v3 = ((li & 1) == 0) ? (v3 * cv - px * sv) : (px * sv + v3 * cv);
            unsigned short* d = dstbase + (size_t)t * C_HEAD;
            d[0 * 16 + li] = f2bf(v0);
            d[1 * 16 + li] = f2bf(v1);
            d[2 * 16 + li] = f2bf(v2);
            d[3 * 16 + li] = f2bf(v3);
        }
    }
}

// ---------------- Kernel 2: MFMA sliding-window attention ---------------
// grid = B*(T/16) = 512 blocks, 256 thr (4 waves = 4 heads of one t-tile).
// Per wave: S^T[32 keys][16 tokens] = mfma(K, Q); softmax over keys
// (in-register + 2 shfls); P via wave-local LDS relayout; PV = 4x K=32 MFMA.
__global__ __launch_bounds__(256) void attn_mfma_kernel(
    const unsigned short* __restrict__ Qb, const unsigned short* __restrict__ Kb,
    const unsigned short* __restrict__ Vb, unsigned short* __restrict__ Obh)
{
    __shared__ __align__(16) unsigned short v_lds[4 * 512];  // 4 ctiles x [32 keys][16 ch]
    __shared__ __align__(16) char p_lds[4 * 1024];           // per-wave P[16 tok][32 key] bf16
    const int tid = threadIdx.x;
    const int blk = blockIdx.x;
    const int b  = blk >> 7;
    const int t0 = (blk & 127) << 4;

    // stage V rows t0-16 .. t0+15 (ctile-blocked, XOR-swizzled)
    {
        const unsigned short* vsrc = Vb + ((size_t)b * T_SEQ + t0 - 16) * C_HEAD; // may hit zero pad
        int row = tid >> 3;            // key row 0..31
        int a8  = tid & 7;             // 8-channel group
        ushort8 v = *(const ushort8*)(vsrc + row * 64 + a8 * 8);
        int byte = (a8 >> 1) * 1024 + row * 32 + (a8 & 1) * 16;
        byte ^= (row & 12) << 3;
        *(ushort8*)((char*)v_lds + byte) = v;
    }
    __syncthreads();

    const int h  = tid >> 6;
    const int l  = tid & 63;
    const int g  = l >> 4;
    const int li = l & 15;

    // Q fragments (B-operand): Q[token=li][c = g*8 + ks*32 ..]
    const unsigned short* qbase = Qb + ((size_t)(b * NH + h) * T_SEQ + t0) * C_HEAD;
    bf16x8 qf0 = *(const bf16x8*)(qbase + li * 64 + g * 8);
    bf16x8 qf1 = *(const bf16x8*)(qbase + li * 64 + 32 + g * 8);

    // S^T = K . Q^T, two 16-key tiles
    const unsigned short* kbase = Kb + ((size_t)b * T_SEQ + t0 - 16) * C_HEAD;
    f32x4 st[2];
    #pragma unroll
    for (int tile = 0; tile < 2; ++tile) {
        const unsigned short* kt = kbase + (size_t)tile * 16 * C_HEAD;
        bf16x8 kf0 = *(const bf16x8*)(kt + li * 64 + g * 8);
        bf16x8 kf1 = *(const bf16x8*)(kt + li * 64 + 32 + g * 8);
        f32x4 acc = {};
        acc = __builtin_amdgcn_mfma_f32_16x16x32_bf16(kf0, qf0, acc, 0, 0, 0);
        acc = __builtin_amdgcn_mfma_f32_16x16x32_bf16(kf1, qf1, acc, 0, 0, 0);
        st[tile] = acc;
    }

    // mask + scale; softmax over 32 keys (8 in-lane + quadrant shfls)
    float p[8];
    float mx = -1e30f;
    #pragma unroll
    for (int tile = 0; tile < 2; ++tile) {
        #pragma unroll
        for (int r = 0; r < 4; ++r) {
            int krel = tile * 16 - 16 + g * 4 + r;   // key - t0
            int dd = li - krel;                       // token - key
            bool ok = ((unsigned)dd < 16u) && (t0 + krel >= 0);
            float v = ok ? st[tile][r] * 0.125f : -1e30f;
            p[tile * 4 + r] = v;
            mx = fmaxf(mx, v);
        }
    }
    mx = fmaxf(mx, __shfl_xor(mx, 16));
    mx = fmaxf(mx, __shfl_xor(mx, 32));
    float sum = 0.f;
    #pragma unroll
    for (int i = 0; i < 8; ++i) { p[i] = __expf(p[i] - mx); sum += p[i]; }
    sum += __shfl_xor(sum, 16);
    sum += __shfl_xor(sum, 32);
    const float inv = 1.0f / sum;

    // P -> wave-local LDS (token-major [li][key], XOR swizzle), then read
    // back the K=32 A-fragment: lane(g,li) holds keys g*8..g*8+7 of token li.
    bf16x8 paf;
    {
        char* pbase = p_lds + h * 1024;
        uint2 w0, w1;
        w0.x = (unsigned)f2bf(p[0] * inv) | ((unsigned)f2bf(p[1] * inv) << 16);
        w0.y = (unsigned)f2bf(p[2] * inv) | ((unsigned)f2bf(p[3] * inv) << 16);
        w1.x = (unsigned)f2bf(p[4] * inv) | ((unsigned)f2bf(p[5] * inv) << 16);
        w1.y = (unsigned)f2bf(p[6] * inv) | ((unsigned)f2bf(p[7] * inv) << 16);
        const int sw = (li & 3) << 4;
        *(uint2*)(pbase + ((li * 64 + 0 * 32 + g * 8) ^ sw)) = w0;
        *(uint2*)(pbase + ((li * 64 + 1 * 32 + g * 8) ^ sw)) = w1;
        asm volatile("s_waitcnt lgkmcnt(0)" ::: "memory");
        paf = *(const bf16x8*)(pbase + ((li * 64 + g * 16) ^ sw));
    }

    // PV: O[16 tok][64 ch] = P[16 tok][32 key] x V[32 key][64 ch], 4 ctiles
    f32x4 o[4] = {};
    #pragma unroll
    for (int ctile = 0; ctile < 4; ++ctile) {
        bf16x8 vf;
        #pragma unroll
        for (int j = 0; j < 8; ++j) {
            int key = g * 8 + j;
            int byte = ctile * 1024 + key * 32 + li * 2;
            byte ^= (key & 12) << 3;
            vf[j] = *(const short*)((const char*)v_lds + byte);
        }
        o[ctile] = __builtin_amdgcn_mfma_f32_16x16x32_bf16(paf, vf, o[ctile], 0, 0, 0);
    }

    // epilogue: inverse rope on chans 48..63 (ctile 3), store bf16
    const float th = powf(10000.0f, -0.125f * (float)(li >> 1));
    #pragma unroll
    for (int r = 0; r < 4; ++r) {
        const int t = t0 + g * 4 + r;
        float o3 = o[3][r];
        float po = __shfl_xor(o3, 1);
        float fr = (float)t * th;
        float cv = cosf(fr), sv = sinf(fr);
        o3 = ((li & 1) == 0) ? (o3 * cv + po * sv) : (-po * sv + o3 * cv);
        unsigned short* dst = Obh + ((size_t)b * T_SEQ + t) * DMODEL + h * C_HEAD;
        dst[0 * 16 + li] = f2bf(o[0][r]);
        dst[1 * 16 + li] = f2bf(o[1][r]);
        dst[2 * 16 + li] = f2bf(o[2][r]);
        dst[3 * 16 + li] = f2bf(o3);
    }
}

// ---------------- Kernel 3: fused gates + output projection (MFMA) ------
__global__ __launch_bounds__(256) void out_mfma_kernel(
    const unsigned short* __restrict__ Obh, const unsigned short* __restrict__ Wallb,
    const float* __restrict__ bg0, const float* __restrict__ bg1,
    const float* __restrict__ bout, float* __restrict__ out)
{
    __shared__ __align__(16) unsigned short o_tile[32 * 256];
    __shared__ __align__(16) unsigned short p_tile[32 * 128];
    const int tid = threadIdx.x;
    const int row0 = blockIdx.x * 32;
    const unsigned short* Wg0b  = Wallb + 98304;
    const unsigned short* Wg1b  = Wallb + 106496;
    const unsigned short* Woutb = Wallb + 114688;

    {
        const unsigned short* osrc = Obh + (size_t)row0 * DMODEL;
        for (int idx = tid; idx < 1024; idx += 256) {
            int row = idx >> 5, ch = idx & 31;
            int byte = row * 512 + ch * 16;
            byte ^= (row & 7) << 4;
            *(ushort8*)((char*)o_tile + byte) = *(const ushort8*)(osrc + row * 256 + ch * 8);
        }
    }
    __syncthreads();

    const int w = tid >> 6;
    const int l = tid & 63;
    const int q = l >> 4, li = l & 15;
    const int gate = w >> 1, half = w & 1;
    const unsigned short* Wgb = gate ? Wg1b : Wg0b;
    const float* bg = gate ? bg1 : bg0;

    {
        f32x4 accp[2][2] = {};
        #pragma unroll
        for (int ks = 0; ks < 4; ++ks) {
            const int k0 = ks * 32;
            bf16x8 a[2];
            #pragma unroll
            for (int mf = 0; mf < 2; ++mf) {
                int row = mf * 16 + li;
                int byte = row * 512 + (gate * 128 + k0 + q * 8) * 2;
                byte ^= (row & 7) << 4;
                a[mf] = *(const bf16x8*)((const char*)o_tile + byte);
            }
            #pragma unroll
            for (int nf = 0; nf < 2; ++nf) {
                const int cl = half * 32 + nf * 16 + li;
                bf16x8 bfr = *(const bf16x8*)(Wgb + (size_t)cl * 128 + k0 + q * 8);
                accp[0][nf] = __builtin_amdgcn_mfma_f32_16x16x32_bf16(a[0], bfr, accp[0][nf], 0, 0, 0);
                accp[1][nf] = __builtin_amdgcn_mfma_f32_16x16x32_bf16(a[1], bfr, accp[1][nf], 0, 0, 0);
            }
        }
        #pragma unroll
        for (int nf = 0; nf < 2; ++nf) {
            const int cl = half * 32 + nf * 16 + li;
            const int pcol = gate * 64 + cl;
            const float bb = bg[cl];
            #pragma unroll
            for (int mf = 0; mf < 2; ++mf) {
                #pragma unroll
                for (int r = 0; r < 4; ++r) {
                    int row = mf * 16 + q * 4 + r;
                    int byte = row * 256 + pcol * 2;
                    byte ^= (row & 7) << 4;
                    *(unsigned short*)((char*)p_tile + byte) = f2bf(accp[mf][nf][r] + bb);
                }
            }
        }
    }
    __syncthreads();

    {
        f32x4 acco[2][4] = {};
        #pragma unroll
        for (int ks = 0; ks < 4; ++ks) {
            const int k0 = ks * 32;
            bf16x8 a[2];
            #pragma unroll
            for (int mf = 0; mf < 2; ++mf) {
                int row = mf * 16 + li;
                int byte = row * 256 + (k0 + q * 8) * 2;
                byte ^= (row & 7) << 4;
                a[mf] = *(const bf16x8*)((const char*)p_tile + byte);
            }
            #pragma unroll
            for (int nf = 0; nf < 4; ++nf) {
                const int col = w * 64 + nf * 16 + li;
                bf16x8 bfr = *(const bf16x8*)(Woutb + (size_t)col * 128 + k0 + q * 8);
                acco[0][nf] = __builtin_amdgcn_mfma_f32_16x16x32_bf16(a[0], bfr, acco[0][nf], 0, 0, 0);
                acco[1][nf] = __builtin_amdgcn_mfma_f32_16x16x32_bf16(a[1], bfr, acco[1][nf], 0, 0, 0);
            }
        }
        #pragma unroll
        for (int nf = 0; nf < 4; ++nf) {
            const int col = w * 64 + nf * 16 + li;
            const float bb = bout[col];
            #pragma unroll
            for (int mf = 0; mf < 2; ++mf) {
                #pragma unroll
                for (int r = 0; r < 4; ++r) {
                    const int row = mf * 16 + q * 4 + r;
                    out[(size_t)(row0 + row) * DMODEL + col] = acco[mf][nf][r] + bb;
                }
            }
        }
    }
}

extern "C" void kernel_launch(void* const* d_in, const int* in_sizes, int n_in,
                              void* d_out, int out_size, void* d_ws, size_t ws_size,
                              hipStream_t stream) {
    const float* H    = (const float*)d_in[0];
    const float* WQ   = (const float*)d_in[1];
    const float* WK   = (const float*)d_in[2];
    const float* WV   = (const float*)d_in[3];
    const float* wq   = (const float*)d_in[4];
    const float* wk   = (const float*)d_in[5];
    const float* wv   = (const float*)d_in[6];
    const float* Wg0  = (const float*)d_in[7];
    const float* bg0  = (const float*)d_in[8];
    const float* Wg1  = (const float*)d_in[9];
    const float* bg1  = (const float*)d_in[10];
    const float* Wout = (const float*)d_in[11];
    const float* bout = (const float*)d_in[12];
    float* out = (float*)d_out;

    char* ws = (char*)d_ws;
    unsigned short* Hb    = (unsigned short*)ws;                  // 4,194,304 B
    unsigned short* Wallb = (unsigned short*)(ws + 4194304);      //   294,912 B
    unsigned short* Qb    = (unsigned short*)(ws + 4489216);      // 4,194,304 B
    unsigned short* Kpad  = (unsigned short*)(ws + 8683520);      //     2,048 B
    unsigned short* Kb    = (unsigned short*)(ws + 8685568);      // 1,048,576 B
    unsigned short* Vpad  = (unsigned short*)(ws + 9734144);      //     2,048 B
    unsigned short* Vb    = (unsigned short*)(ws + 9736192);      // 1,048,576 B
    unsigned short* Obh   = (unsigned short*)(ws + 10784768);     // 4,194,304 B

    conv_h_kernel<<<1024, 256, 0, stream>>>(H, Hb);
    conv_w_kernel<<<73, 256, 0, stream>>>(WQ, WK, WV, Wg0, Wg1, Wout, Wallb, Kpad, Vpad);
    qkv_mfma_kernel<<<256, 384, 0, stream>>>(Hb, Wallb, wq, wk, wv, Qb, Kb, Vb);
    attn_mfma_kernel<<<B_SZ * T_SEQ / 16, 256, 0, stream>>>(Qb, Kb, Vb, Obh);
    out_mfma_kernel<<<256, 256, 0, stream>>>(Obh, Wallb, bg0, bg1, bout, out);
}

// Round 6
// 40.455 us; speedup vs baseline: 3.8862x; 1.0543x over previous
//
#include <hip/hip_runtime.h>
#include <math.h>

#define T_SEQ 2048
#define DMODEL 256
#define C_HEAD 64
#define NH 4
#define NWIN 16
#define B_SZ 4

typedef __attribute__((ext_vector_type(8))) short bf16x8;
typedef __attribute__((ext_vector_type(8))) unsigned short ushort8;
typedef __attribute__((ext_vector_type(4))) float f32x4;

static __device__ __forceinline__ unsigned short f2bf(float f) {
    union { float f; unsigned int u; } v; v.f = f;
    unsigned int r = v.u + 0x7FFFu + ((v.u >> 16) & 1u);
    return (unsigned short)(r >> 16);
}

// ---------------- convert all weights into one packed bf16 region -------
// layout (elems): WQ[0,65536) WK[65536,81920) WV[81920,98304)
//                 Wg0[98304,106496) Wg1[106496,114688) Wout[114688,147456)
// block 72 zeroes the K/V pad rows.
__global__ __launch_bounds__(256) void conv_w_kernel(
    const float* __restrict__ WQ, const float* __restrict__ WK,
    const float* __restrict__ WV, const float* __restrict__ Wg0,
    const float* __restrict__ Wg1, const float* __restrict__ Wout,
    unsigned short* __restrict__ dst,
    unsigned short* __restrict__ kpad, unsigned short* __restrict__ vpad) {
    const int tid = threadIdx.x;
    if (blockIdx.x == 72) {
        ushort8 z = {0, 0, 0, 0, 0, 0, 0, 0};
        if (tid < 128) *(ushort8*)(kpad + tid * 8) = z;
        else           *(ushort8*)(vpad + (tid - 128) * 8) = z;
        return;
    }
    const int i = blockIdx.x * 256 + tid;               // 18432 vec8
    const long e = (long)i * 8;
    const float* s; long off;
    if      (e < 65536)  { s = WQ;   off = e; }
    else if (e < 81920)  { s = WK;   off = e - 65536; }
    else if (e < 98304)  { s = WV;   off = e - 81920; }
    else if (e < 106496) { s = Wg0;  off = e - 98304; }
    else if (e < 114688) { s = Wg1;  off = e - 106496; }
    else                 { s = Wout; off = e - 114688; }
    const float4* s4 = (const float4*)(s + off);
    float4 a = s4[0], b = s4[1];
    ushort8 o;
    o[0] = f2bf(a.x); o[1] = f2bf(a.y); o[2] = f2bf(a.z); o[3] = f2bf(a.w);
    o[4] = f2bf(b.x); o[5] = f2bf(b.y); o[6] = f2bf(b.z); o[7] = f2bf(b.w);
    *(ushort8*)(dst + e) = o;
}

// ---------------- Kernel 1: MFMA QKV projection + RMSNorm + RoPE --------
// grid = 8192/32 = 256 blocks, 768 thr (12 waves). Wave w: col group
// g=w>>1 (64 cols: Q heads 0..3, K, V), row half rh=w&1 (16 of 32 tokens).
// Stages H directly from f32 (inline bf16 conversion). Outputs bf16.
__global__ __launch_bounds__(768) void qkv_mfma_kernel(
    const float* __restrict__ H, const unsigned short* __restrict__ Wb,
    const float* __restrict__ wq, const float* __restrict__ wk,
    const float* __restrict__ wv,
    unsigned short* __restrict__ Qb, unsigned short* __restrict__ Kb,
    unsigned short* __restrict__ Vb)
{
    __shared__ __align__(16) unsigned short lds_a[32 * 256];   // 16KB, swizzled
    const int tid = threadIdx.x;
    const int row0 = blockIdx.x * 32;
    const int b = row0 >> 11;
    const int tbase = row0 & (T_SEQ - 1);

    {
        const float* hsrc = H + (size_t)row0 * DMODEL;
        for (int idx = tid; idx < 1024; idx += 768) {
            int row = idx >> 5, ch = idx & 31;
            const float4* s4 = (const float4*)(hsrc + row * 256 + ch * 8);
            float4 a = s4[0], c = s4[1];
            ushort8 o;
            o[0] = f2bf(a.x); o[1] = f2bf(a.y); o[2] = f2bf(a.z); o[3] = f2bf(a.w);
            o[4] = f2bf(c.x); o[5] = f2bf(c.y); o[6] = f2bf(c.z); o[7] = f2bf(c.w);
            int byte = row * 512 + ch * 16;
            byte ^= (row & 7) << 4;
            *(ushort8*)((char*)lds_a + byte) = o;
        }
    }
    __syncthreads();

    const int w = tid >> 6;
    const int g = w >> 1;          // col group 0..5
    const int rh = w & 1;          // row half
    const int l = tid & 63;
    const int q = l >> 4, li = l & 15;

    f32x4 acc[4] = {};
    #pragma unroll
    for (int ks = 0; ks < 8; ++ks) {
        const int k0 = ks * 32;
        const int row = rh * 16 + li;
        int byte = row * 512 + (k0 + q * 8) * 2;
        byte ^= (row & 7) << 4;
        bf16x8 a = *(const bf16x8*)((const char*)lds_a + byte);
        #pragma unroll
        for (int nf = 0; nf < 4; ++nf) {
            const int col = g * 64 + nf * 16 + li;
            bf16x8 bfr = *(const bf16x8*)(Wb + (size_t)col * 256 + k0 + q * 8);
            acc[nf] = __builtin_amdgcn_mfma_f32_16x16x32_bf16(a, bfr, acc[nf], 0, 0, 0);
        }
    }

    float gw[4];
    #pragma unroll
    for (int nf = 0; nf < 4; ++nf) {
        const int c = nf * 16 + li;
        gw[nf] = (g < 4) ? wq[g * 64 + c] : (g == 4 ? wk[c] : wv[c]);
    }
    const float th = powf(10000.0f, -0.125f * (float)(li >> 1));

    unsigned short* dstbase;
    if (g < 4)       dstbase = Qb + ((size_t)(b * NH + g) * T_SEQ) * C_HEAD;
    else if (g == 4) dstbase = Kb + ((size_t)b * T_SEQ) * C_HEAD;
    else             dstbase = Vb + ((size_t)b * T_SEQ) * C_HEAD;

    #pragma unroll
    for (int r = 0; r < 4; ++r) {
        float x0 = acc[0][r], x1 = acc[1][r];
        float x2 = acc[2][r], x3 = acc[3][r];
        float ss = x0 * x0 + x1 * x1 + x2 * x2 + x3 * x3;
        ss += __shfl_xor(ss, 1);
        ss += __shfl_xor(ss, 2);
        ss += __shfl_xor(ss, 4);
        ss += __shfl_xor(ss, 8);
        const float rinv = rsqrtf(ss * (1.0f / 64.0f) + 1e-8f);
        const int t = tbase + rh * 16 + q * 4 + r;
        float v0 = x0 * rinv * gw[0];
        float v1 = x1 * rinv * gw[1];
        float v2 = x2 * rinv * gw[2];
        float v3 = x3 * rinv * gw[3];
        float px = __shfl_xor(v3, 1);
        float fr = (float)t * th;
        float cv = cosf(fr), sv = sinf(fr);
        v3 = ((li & 1) == 0) ? (v3 * cv - px * sv) : (px * sv + v3 * cv);
        unsigned short* d = dstbase + (size_t)t * C_HEAD;
        d[0 * 16 + li] = f2bf(v0);
        d[1 * 16 + li] = f2bf(v1);
        d[2 * 16 + li] = f2bf(v2);
        d[3 * 16 + li] = f2bf(v3);
    }
}

// ---------------- Kernel 2: attention + gates + output projection -------
// grid = B*(T/16) = 512 blocks, 256 thr (4 waves = 4 heads of one t-tile).
// Stage 1: per-wave MFMA attention -> O[16 tok][64 ch] in regs.
// Stage 2: O -> swizzled LDS; gate projections (K=128); out proj (K=128).
__global__ __launch_bounds__(256) void attn_out_kernel(
    const unsigned short* __restrict__ Qb, const unsigned short* __restrict__ Kb,
    const unsigned short* __restrict__ Vb, const unsigned short* __restrict__ Wallb,
    const float* __restrict__ bg0, const float* __restrict__ bg1,
    const float* __restrict__ bout, float* __restrict__ out)
{
    __shared__ __align__(16) unsigned short v_lds[4 * 512];  // 4 ctiles x [32 keys][16 ch]
    __shared__ __align__(16) char p_att[4 * 1024];           // per-wave P[16 tok][32 key]
    __shared__ __align__(16) unsigned short o_lds[16 * 256]; // 8KB, swizzled
    __shared__ __align__(16) unsigned short p_lds[16 * 128]; // 4KB, swizzled
    const int tid = threadIdx.x;
    const int blk = blockIdx.x;
    const int b  = blk >> 7;
    const int t0 = (blk & 127) << 4;

    const unsigned short* Wg0b  = Wallb + 98304;
    const unsigned short* Wg1b  = Wallb + 106496;
    const unsigned short* Woutb = Wallb + 114688;

    // stage V rows t0-16 .. t0+15 (ctile-blocked, XOR-swizzled)
    {
        const unsigned short* vsrc = Vb + ((size_t)b * T_SEQ + t0 - 16) * C_HEAD;
        int row = tid >> 3;
        int a8  = tid & 7;
        ushort8 v = *(const ushort8*)(vsrc + row * 64 + a8 * 8);
        int byte = (a8 >> 1) * 1024 + row * 32 + (a8 & 1) * 16;
        byte ^= (row & 12) << 3;
        *(ushort8*)((char*)v_lds + byte) = v;
    }
    __syncthreads();

    const int h  = tid >> 6;
    const int l  = tid & 63;
    const int g  = l >> 4;
    const int q  = g;              // quadrant alias used by projection phases
    const int li = l & 15;

    const unsigned short* qbase = Qb + ((size_t)(b * NH + h) * T_SEQ + t0) * C_HEAD;
    bf16x8 qf0 = *(const bf16x8*)(qbase + li * 64 + g * 8);
    bf16x8 qf1 = *(const bf16x8*)(qbase + li * 64 + 32 + g * 8);

    const unsigned short* kbase = Kb + ((size_t)b * T_SEQ + t0 - 16) * C_HEAD;
    f32x4 st[2];
    #pragma unroll
    for (int tile = 0; tile < 2; ++tile) {
        const unsigned short* kt = kbase + (size_t)tile * 16 * C_HEAD;
        bf16x8 kf0 = *(const bf16x8*)(kt + li * 64 + g * 8);
        bf16x8 kf1 = *(const bf16x8*)(kt + li * 64 + 32 + g * 8);
        f32x4 acc = {};
        acc = __builtin_amdgcn_mfma_f32_16x16x32_bf16(kf0, qf0, acc, 0, 0, 0);
        acc = __builtin_amdgcn_mfma_f32_16x16x32_bf16(kf1, qf1, acc, 0, 0, 0);
        st[tile] = acc;
    }

    float p[8];
    float mx = -1e30f;
    #pragma unroll
    for (int tile = 0; tile < 2; ++tile) {
        #pragma unroll
        for (int r = 0; r < 4; ++r) {
            int krel = tile * 16 - 16 + g * 4 + r;
            int dd = li - krel;
            bool ok = ((unsigned)dd < 16u) && (t0 + krel >= 0);
            float v = ok ? st[tile][r] * 0.125f : -1e30f;
            p[tile * 4 + r] = v;
            mx = fmaxf(mx, v);
        }
    }
    mx = fmaxf(mx, __shfl_xor(mx, 16));
    mx = fmaxf(mx, __shfl_xor(mx, 32));
    float sum = 0.f;
    #pragma unroll
    for (int i = 0; i < 8; ++i) { p[i] = __expf(p[i] - mx); sum += p[i]; }
    sum += __shfl_xor(sum, 16);
    sum += __shfl_xor(sum, 32);
    const float inv = 1.0f / sum;

    // P -> wave-local LDS relayout to K=32 A-fragment
    bf16x8 paf;
    {
        char* pbase = p_att + h * 1024;
        uint2 w0, w1;
        w0.x = (unsigned)f2bf(p[0] * inv) | ((unsigned)f2bf(p[1] * inv) << 16);
        w0.y = (unsigned)f2bf(p[2] * inv) | ((unsigned)f2bf(p[3] * inv) << 16);
        w1.x = (unsigned)f2bf(p[4] * inv) | ((unsigned)f2bf(p[5] * inv) << 16);
        w1.y = (unsigned)f2bf(p[6] * inv) | ((unsigned)f2bf(p[7] * inv) << 16);
        const int sw = (li & 3) << 4;
        *(uint2*)(pbase + ((li * 64 + 0 * 32 + g * 8) ^ sw)) = w0;
        *(uint2*)(pbase + ((li * 64 + 1 * 32 + g * 8) ^ sw)) = w1;
        asm volatile("s_waitcnt lgkmcnt(0)" ::: "memory");
        paf = *(const bf16x8*)(pbase + ((li * 64 + g * 16) ^ sw));
    }

    // PV: O[16 tok][64 ch]
    f32x4 o[4] = {};
    #pragma unroll
    for (int ctile = 0; ctile < 4; ++ctile) {
        bf16x8 vf;
        #pragma unroll
        for (int j = 0; j < 8; ++j) {
            int key = g * 8 + j;
            int byte = ctile * 1024 + key * 32 + li * 2;
            byte ^= (key & 12) << 3;
            vf[j] = *(const short*)((const char*)v_lds + byte);
        }
        o[ctile] = __builtin_amdgcn_mfma_f32_16x16x32_bf16(paf, vf, o[ctile], 0, 0, 0);
    }

    // inverse rope on chans 48..63 (ctile 3); write O to swizzled LDS (bf16)
    const float th = powf(10000.0f, -0.125f * (float)(li >> 1));
    #pragma unroll
    for (int r = 0; r < 4; ++r) {
        const int t = t0 + g * 4 + r;
        float o3 = o[3][r];
        float po = __shfl_xor(o3, 1);
        float fr = (float)t * th;
        float cv = cosf(fr), sv = sinf(fr);
        o3 = ((li & 1) == 0) ? (o3 * cv + po * sv) : (-po * sv + o3 * cv);
        const int row = g * 4 + r;
        #pragma unroll
        for (int ctile = 0; ctile < 4; ++ctile) {
            const int col = h * 64 + ctile * 16 + li;
            int byte = row * 512 + col * 2;
            byte ^= (row & 7) << 4;
            float val = (ctile == 3) ? o3 : o[ctile][r];
            *(unsigned short*)((char*)o_lds + byte) = f2bf(val);
        }
    }
    __syncthreads();

    // phase 1: gates. wave h: gate=h>>1, half=h&1; p-cols half*32+nf*16+li
    const int gate = h >> 1, half = h & 1;
    const unsigned short* Wgb = gate ? Wg1b : Wg0b;
    const float* bg = gate ? bg1 : bg0;
    {
        f32x4 accp[2] = {};
        #pragma unroll
        for (int ks = 0; ks < 4; ++ks) {
            const int k0 = ks * 32;
            int byte = li * 512 + (gate * 128 + k0 + q * 8) * 2;
            byte ^= (li & 7) << 4;
            bf16x8 a = *(const bf16x8*)((const char*)o_lds + byte);
            #pragma unroll
            for (int nf = 0; nf < 2; ++nf) {
                const int cl = half * 32 + nf * 16 + li;
                bf16x8 bfr = *(const bf16x8*)(Wgb + (size_t)cl * 128 + k0 + q * 8);
                accp[nf] = __builtin_amdgcn_mfma_f32_16x16x32_bf16(a, bfr, accp[nf], 0, 0, 0);
            }
        }
        #pragma unroll
        for (int nf = 0; nf < 2; ++nf) {
            const int cl = half * 32 + nf * 16 + li;
            const int pcol = gate * 64 + cl;
            const float bb = bg[cl];
            #pragma unroll
            for (int r = 0; r < 4; ++r) {
                int row = q * 4 + r;
                int byte = row * 256 + pcol * 2;
                byte ^= (row & 7) << 4;
                *(unsigned short*)((char*)p_lds + byte) = f2bf(accp[nf][r] + bb);
            }
        }
    }
    __syncthreads();

    // phase 2: out cols = h*64 + nf*16 + li, K = 128 (p_lds)
    {
        f32x4 acco[4] = {};
        #pragma unroll
        for (int ks = 0; ks < 4; ++ks) {
            const int k0 = ks * 32;
            int byte = li * 256 + (k0 + q * 8) * 2;
            byte ^= (li & 7) << 4;
            bf16x8 a = *(const bf16x8*)((const char*)p_lds + byte);
            #pragma unroll
            for (int nf = 0; nf < 4; ++nf) {
                const int col = h * 64 + nf * 16 + li;
                bf16x8 bfr = *(const bf16x8*)(Woutb + (size_t)col * 128 + k0 + q * 8);
                acco[nf] = __builtin_amdgcn_mfma_f32_16x16x32_bf16(a, bfr, acco[nf], 0, 0, 0);
            }
        }
        #pragma unroll
        for (int nf = 0; nf < 4; ++nf) {
            const int col = h * 64 + nf * 16 + li;
            const float bb = bout[col];
            #pragma unroll
            for (int r = 0; r < 4; ++r) {
                const int row = q * 4 + r;
                out[(size_t)(b * T_SEQ + t0 + row) * DMODEL + col] = acco[nf][r] + bb;
            }
        }
    }
}

extern "C" void kernel_launch(void* const* d_in, const int* in_sizes, int n_in,
                              void* d_out, int out_size, void* d_ws, size_t ws_size,
                              hipStream_t stream) {
    const float* H    = (const float*)d_in[0];
    const float* WQ   = (const float*)d_in[1];
    const float* WK   = (const float*)d_in[2];
    const float* WV   = (const float*)d_in[3];
    const float* wq   = (const float*)d_in[4];
    const float* wk   = (const float*)d_in[5];
    const float* wv   = (const float*)d_in[6];
    const float* Wg0  = (const float*)d_in[7];
    const float* bg0  = (const float*)d_in[8];
    const float* Wg1  = (const float*)d_in[9];
    const float* bg1  = (const float*)d_in[10];
    const float* Wout = (const float*)d_in[11];
    const float* bout = (const float*)d_in[12];
    float* out = (float*)d_out;

    char* ws = (char*)d_ws;
    unsigned short* Wallb = (unsigned short*)ws;                  //   294,912 B
    unsigned short* Qb    = (unsigned short*)(ws + 524288);       // 4,194,304 B
    unsigned short* Kpad  = (unsigned short*)(ws + 4718592);      //     2,048 B
    unsigned short* Kb    = (unsigned short*)(ws + 4720640);      // 1,048,576 B
    unsigned short* Vpad  = (unsigned short*)(ws + 5769216);      //     2,048 B
    unsigned short* Vb    = (unsigned short*)(ws + 5771264);      // 1,048,576 B

    conv_w_kernel<<<73, 256, 0, stream>>>(WQ, WK, WV, Wg0, Wg1, Wout, Wallb, Kpad, Vpad);
    qkv_mfma_kernel<<<256, 768, 0, stream>>>(H, Wallb, wq, wk, wv, Qb, Kb, Vb);
    attn_out_kernel<<<B_SZ * T_SEQ / 16, 256, 0, stream>>>(Qb, Kb, Vb, Wallb, bg0, bg1, bout, out);
}

// Round 7
// 30.595 us; speedup vs baseline: 5.1387x; 1.3223x over previous
//
#include <hip/hip_runtime.h>
#include <math.h>

#define T_SEQ 2048
#define DMODEL 256
#define C_HEAD 64
#define NH 4
#define NWIN 16
#define B_SZ 4

typedef __attribute__((ext_vector_type(8))) short bf16x8;
typedef __attribute__((ext_vector_type(8))) unsigned short ushort8;
typedef __attribute__((ext_vector_type(4))) float f32x4;

static __device__ __forceinline__ unsigned short f2bf(float f) {
    union { float f; unsigned int u; } v; v.f = f;
    unsigned int r = v.u + 0x7FFFu + ((v.u >> 16) & 1u);
    return (unsigned short)(r >> 16);
}

// ---------------- convert weights into FRAGMENT-MAJOR packed bf16 -------
// Region 1 (K=256): concat cols [WQ(256) WK(64) WV(64)] = 384 cols.
//   elem offset = ((col>>4)*8 + (k>>5))*512 + ((k>>3)&3)*128 + (col&15)*8 + (k&7)
//   total 98304 elems.
// Region 2 (K=128): concat cols [Wg0(64) Wg1(64) Wout(256)] = 384 cols, at +98304.
//   elem offset = ((col>>4)*4 + (k>>5))*512 + ((k>>3)&3)*128 + (col&15)*8 + (k&7)
//   total 49152 elems.
// Every MFMA B-load becomes base + lane*16 (fully coalesced).
// block 72 zeroes the K/V pad rows.
__global__ __launch_bounds__(256) void conv_w_kernel(
    const float* __restrict__ WQ, const float* __restrict__ WK,
    const float* __restrict__ WV, const float* __restrict__ Wg0,
    const float* __restrict__ Wg1, const float* __restrict__ Wout,
    unsigned short* __restrict__ dst,
    unsigned short* __restrict__ kpad, unsigned short* __restrict__ vpad) {
    const int tid = threadIdx.x;
    if (blockIdx.x == 72) {
        ushort8 z = {0, 0, 0, 0, 0, 0, 0, 0};
        if (tid < 128) *(ushort8*)(kpad + tid * 8) = z;
        else           *(ushort8*)(vpad + (tid - 128) * 8) = z;
        return;
    }
    const int i = blockIdx.x * 256 + tid;               // 18432 vec8
    const float* s; long off; long doff;
    if (i < 12288) {                                    // K=256 region
        const long e = (long)i * 8;
        const int col = (int)(e >> 8), k = (int)(e & 255);
        if      (col < 256) { s = WQ; off = (long)col * 256 + k; }
        else if (col < 320) { s = WK; off = (long)(col - 256) * 256 + k; }
        else                { s = WV; off = (long)(col - 320) * 256 + k; }
        doff = ((long)(col >> 4) * 8 + (k >> 5)) * 512 + ((k >> 3) & 3) * 128 + (col & 15) * 8;
    } else {                                            // K=128 region
        const long e = (long)(i - 12288) * 8;
        const int col = (int)(e >> 7), k = (int)(e & 127);
        if      (col < 64)  { s = Wg0; off = (long)col * 128 + k; }
        else if (col < 128) { s = Wg1; off = (long)(col - 64) * 128 + k; }
        else                { s = Wout; off = (long)(col - 128) * 128 + k; }
        doff = 98304 + ((long)(col >> 4) * 4 + (k >> 5)) * 512 + ((k >> 3) & 3) * 128 + (col & 15) * 8;
    }
    const float4* s4 = (const float4*)(s + off);
    float4 a = s4[0], b = s4[1];
    ushort8 o;
    o[0] = f2bf(a.x); o[1] = f2bf(a.y); o[2] = f2bf(a.z); o[3] = f2bf(a.w);
    o[4] = f2bf(b.x); o[5] = f2bf(b.y); o[6] = f2bf(b.z); o[7] = f2bf(b.w);
    *(ushort8*)(dst + doff) = o;
}

// ---------------- Kernel 1: MFMA QKV projection + RMSNorm + RoPE --------
// grid = 8192/32 = 256 blocks, 384 thr (6 waves). Wave g = col group
// g*64..g*64+63 (Q heads 0..3, K, V), acc[2][4] (M=32). Packed-W B-loads
// are coalesced: base + lane*16. Stages H from f32. Outputs bf16.
__global__ __launch_bounds__(384) void qkv_mfma_kernel(
    const float* __restrict__ H, const unsigned short* __restrict__ Wb,
    const float* __restrict__ wq, const float* __restrict__ wk,
    const float* __restrict__ wv,
    unsigned short* __restrict__ Qb, unsigned short* __restrict__ Kb,
    unsigned short* __restrict__ Vb)
{
    __shared__ __align__(16) unsigned short lds_a[32 * 256];   // 16KB, swizzled
    const int tid = threadIdx.x;
    const int row0 = blockIdx.x * 32;
    const int b = row0 >> 11;
    const int tbase = row0 & (T_SEQ - 1);

    {
        const float* hsrc = H + (size_t)row0 * DMODEL;
        for (int idx = tid; idx < 1024; idx += 384) {
            int row = idx >> 5, ch = idx & 31;
            const float4* s4 = (const float4*)(hsrc + row * 256 + ch * 8);
            float4 a = s4[0], c = s4[1];
            ushort8 o;
            o[0] = f2bf(a.x); o[1] = f2bf(a.y); o[2] = f2bf(a.z); o[3] = f2bf(a.w);
            o[4] = f2bf(c.x); o[5] = f2bf(c.y); o[6] = f2bf(c.z); o[7] = f2bf(c.w);
            int byte = row * 512 + ch * 16;
            byte ^= (row & 7) << 4;
            *(ushort8*)((char*)lds_a + byte) = o;
        }
    }
    __syncthreads();

    const int g = tid >> 6;        // wave = col group 0..5
    const int l = tid & 63;
    const int q = l >> 4, li = l & 15;
    const int lane16 = l * 8;      // packed-W per-lane elem offset (l*16 bytes)

    f32x4 acc[2][4] = {};
    #pragma unroll
    for (int ks = 0; ks < 8; ++ks) {
        const int k0 = ks * 32;
        bf16x8 a[2];
        #pragma unroll
        for (int mf = 0; mf < 2; ++mf) {
            int row = mf * 16 + li;
            int byte = row * 512 + (k0 + q * 8) * 2;
            byte ^= (row & 7) << 4;
            a[mf] = *(const bf16x8*)((const char*)lds_a + byte);
        }
        #pragma unroll
        for (int nf = 0; nf < 4; ++nf) {
            const int colblk = g * 4 + nf;
            bf16x8 bfr = *(const bf16x8*)(Wb + (size_t)(colblk * 8 + ks) * 512 + lane16);
            acc[0][nf] = __builtin_amdgcn_mfma_f32_16x16x32_bf16(a[0], bfr, acc[0][nf], 0, 0, 0);
            acc[1][nf] = __builtin_amdgcn_mfma_f32_16x16x32_bf16(a[1], bfr, acc[1][nf], 0, 0, 0);
        }
    }

    float gw[4];
    #pragma unroll
    for (int nf = 0; nf < 4; ++nf) {
        const int c = nf * 16 + li;
        gw[nf] = (g < 4) ? wq[g * 64 + c] : (g == 4 ? wk[c] : wv[c]);
    }
    const float th = powf(10000.0f, -0.125f * (float)(li >> 1));

    unsigned short* dstbase;
    if (g < 4)       dstbase = Qb + ((size_t)(b * NH + g) * T_SEQ) * C_HEAD;
    else if (g == 4) dstbase = Kb + ((size_t)b * T_SEQ) * C_HEAD;
    else             dstbase = Vb + ((size_t)b * T_SEQ) * C_HEAD;

    #pragma unroll
    for (int mf = 0; mf < 2; ++mf) {
        #pragma unroll
        for (int r = 0; r < 4; ++r) {
            float x0 = acc[mf][0][r], x1 = acc[mf][1][r];
            float x2 = acc[mf][2][r], x3 = acc[mf][3][r];
            float ss = x0 * x0 + x1 * x1 + x2 * x2 + x3 * x3;
            ss += __shfl_xor(ss, 1);
            ss += __shfl_xor(ss, 2);
            ss += __shfl_xor(ss, 4);
            ss += __shfl_xor(ss, 8);
            const float rinv = rsqrtf(ss * (1.0f / 64.0f) + 1e-8f);
            const int t = tbase + mf * 16 + q * 4 + r;
            float v0 = x0 * rinv * gw[0];
            float v1 = x1 * rinv * gw[1];
            float v2 = x2 * rinv * gw[2];
            float v3 = x3 * rinv * gw[3];
            float px = __shfl_xor(v3, 1);
            float fr = (float)t * th;
            float cv = cosf(fr), sv = sinf(fr);
            v3 = ((li & 1) == 0) ? (v3 * cv - px * sv) : (px * sv + v3 * cv);
            unsigned short* d = dstbase + (size_t)t * C_HEAD;
            d[0 * 16 + li] = f2bf(v0);
            d[1 * 16 + li] = f2bf(v1);
            d[2 * 16 + li] = f2bf(v2);
            d[3 * 16 + li] = f2bf(v3);
        }
    }
}

// ---------------- Kernel 2: attention + gates + output projection -------
// grid = B*(T/16) = 512 blocks, 256 thr (4 waves = 4 heads of one t-tile).
// Stage 1: per-wave MFMA attention -> O[16 tok][64 ch] in regs.
// Stage 2: O -> swizzled LDS; gate projections (K=128); out proj (K=128).
// Projection B-loads use the packed layout (coalesced).
__global__ __launch_bounds__(256) void attn_out_kernel(
    const unsigned short* __restrict__ Qb, const unsigned short* __restrict__ Kb,
    const unsigned short* __restrict__ Vb, const unsigned short* __restrict__ Wallb,
    const float* __restrict__ bg0, const float* __restrict__ bg1,
    const float* __restrict__ bout, float* __restrict__ out)
{
    __shared__ __align__(16) unsigned short v_lds[4 * 512];  // 4 ctiles x [32 keys][16 ch]
    __shared__ __align__(16) char p_att[4 * 1024];           // per-wave P[16 tok][32 key]
    __shared__ __align__(16) unsigned short o_lds[16 * 256]; // 8KB, swizzled
    __shared__ __align__(16) unsigned short p_lds[16 * 128]; // 4KB, swizzled
    const int tid = threadIdx.x;
    const int blk = blockIdx.x;
    const int b  = blk >> 7;
    const int t0 = (blk & 127) << 4;

    const unsigned short* Wpk2 = Wallb + 98304;   // K=128 packed region

    // stage V rows t0-16 .. t0+15 (ctile-blocked, XOR-swizzled)
    {
        const unsigned short* vsrc = Vb + ((size_t)b * T_SEQ + t0 - 16) * C_HEAD;
        int row = tid >> 3;
        int a8  = tid & 7;
        ushort8 v = *(const ushort8*)(vsrc + row * 64 + a8 * 8);
        int byte = (a8 >> 1) * 1024 + row * 32 + (a8 & 1) * 16;
        byte ^= (row & 12) << 3;
        *(ushort8*)((char*)v_lds + byte) = v;
    }
    __syncthreads();

    const int h  = tid >> 6;
    const int l  = tid & 63;
    const int g  = l >> 4;
    const int q  = g;              // quadrant alias used by projection phases
    const int li = l & 15;
    const int lane16 = l * 8;      // packed-W per-lane elem offset

    const unsigned short* qbase = Qb + ((size_t)(b * NH + h) * T_SEQ + t0) * C_HEAD;
    bf16x8 qf0 = *(const bf16x8*)(qbase + li * 64 + g * 8);
    bf16x8 qf1 = *(const bf16x8*)(qbase + li * 64 + 32 + g * 8);

    const unsigned short* kbase = Kb + ((size_t)b * T_SEQ + t0 - 16) * C_HEAD;
    f32x4 st[2];
    #pragma unroll
    for (int tile = 0; tile < 2; ++tile) {
        const unsigned short* kt = kbase + (size_t)tile * 16 * C_HEAD;
        bf16x8 kf0 = *(const bf16x8*)(kt + li * 64 + g * 8);
        bf16x8 kf1 = *(const bf16x8*)(kt + li * 64 + 32 + g * 8);
        f32x4 acc = {};
        acc = __builtin_amdgcn_mfma_f32_16x16x32_bf16(kf0, qf0, acc, 0, 0, 0);
        acc = __builtin_amdgcn_mfma_f32_16x16x32_bf16(kf1, qf1, acc, 0, 0, 0);
        st[tile] = acc;
    }

    float p[8];
    float mx = -1e30f;
    #pragma unroll
    for (int tile = 0; tile < 2; ++tile) {
        #pragma unroll
        for (int r = 0; r < 4; ++r) {
            int krel = tile * 16 - 16 + g * 4 + r;
            int dd = li - krel;
            bool ok = ((unsigned)dd < 16u) && (t0 + krel >= 0);
            float v = ok ? st[tile][r] * 0.125f : -1e30f;
            p[tile * 4 + r] = v;
            mx = fmaxf(mx, v);
        }
    }
    mx = fmaxf(mx, __shfl_xor(mx, 16));
    mx = fmaxf(mx, __shfl_xor(mx, 32));
    float sum = 0.f;
    #pragma unroll
    for (int i = 0; i < 8; ++i) { p[i] = __expf(p[i] - mx); sum += p[i]; }
    sum += __shfl_xor(sum, 16);
    sum += __shfl_xor(sum, 32);
    const float inv = 1.0f / sum;

    // P -> wave-local LDS relayout to K=32 A-fragment
    bf16x8 paf;
    {
        char* pbase = p_att + h * 1024;
        uint2 w0, w1;
        w0.x = (unsigned)f2bf(p[0] * inv) | ((unsigned)f2bf(p[1] * inv) << 16);
        w0.y = (unsigned)f2bf(p[2] * inv) | ((unsigned)f2bf(p[3] * inv) << 16);
        w1.x = (unsigned)f2bf(p[4] * inv) | ((unsigned)f2bf(p[5] * inv) << 16);
        w1.y = (unsigned)f2bf(p[6] * inv) | ((unsigned)f2bf(p[7] * inv) << 16);
        const int sw = (li & 3) << 4;
        *(uint2*)(pbase + ((li * 64 + 0 * 32 + g * 8) ^ sw)) = w0;
        *(uint2*)(pbase + ((li * 64 + 1 * 32 + g * 8) ^ sw)) = w1;
        asm volatile("s_waitcnt lgkmcnt(0)" ::: "memory");
        paf = *(const bf16x8*)(pbase + ((li * 64 + g * 16) ^ sw));
    }

    // PV: O[16 tok][64 ch]
    f32x4 o[4] = {};
    #pragma unroll
    for (int ctile = 0; ctile < 4; ++ctile) {
        bf16x8 vf;
        #pragma unroll
        for (int j = 0; j < 8; ++j) {
            int key = g * 8 + j;
            int byte = ctile * 1024 + key * 32 + li * 2;
            byte ^= (key & 12) << 3;
            vf[j] = *(const short*)((const char*)v_lds + byte);
        }
        o[ctile] = __builtin_amdgcn_mfma_f32_16x16x32_bf16(paf, vf, o[ctile], 0, 0, 0);
    }

    // inverse rope on chans 48..63 (ctile 3); write O to swizzled LDS (bf16)
    const float th = powf(10000.0f, -0.125f * (float)(li >> 1));
    #pragma unroll
    for (int r = 0; r < 4; ++r) {
        const int t = t0 + g * 4 + r;
        float o3 = o[3][r];
        float po = __shfl_xor(o3, 1);
        float fr = (float)t * th;
        float cv = cosf(fr), sv = sinf(fr);
        o3 = ((li & 1) == 0) ? (o3 * cv + po * sv) : (-po * sv + o3 * cv);
        const int row = g * 4 + r;
        #pragma unroll
        for (int ctile = 0; ctile < 4; ++ctile) {
            const int col = h * 64 + ctile * 16 + li;
            int byte = row * 512 + col * 2;
            byte ^= (row & 7) << 4;
            float val = (ctile == 3) ? o3 : o[ctile][r];
            *(unsigned short*)((char*)o_lds + byte) = f2bf(val);
        }
    }
    __syncthreads();

    // phase 1: gates. wave h: gate=h>>1, half=h&1; p-cols half*32+nf*16+li
    const int gate = h >> 1, half = h & 1;
    const float* bg = gate ? bg1 : bg0;
    {
        f32x4 accp[2] = {};
        #pragma unroll
        for (int ks = 0; ks < 4; ++ks) {
            const int k0 = ks * 32;
            int byte = li * 512 + (gate * 128 + k0 + q * 8) * 2;
            byte ^= (li & 7) << 4;
            bf16x8 a = *(const bf16x8*)((const char*)o_lds + byte);
            #pragma unroll
            for (int nf = 0; nf < 2; ++nf) {
                const int colblk = gate * 4 + half * 2 + nf;   // concat col / 16
                bf16x8 bfr = *(const bf16x8*)(Wpk2 + (size_t)(colblk * 4 + ks) * 512 + lane16);
                accp[nf] = __builtin_amdgcn_mfma_f32_16x16x32_bf16(a, bfr, accp[nf], 0, 0, 0);
            }
        }
        #pragma unroll
        for (int nf = 0; nf < 2; ++nf) {
            const int cl = half * 32 + nf * 16 + li;
            const int pcol = gate * 64 + cl;
            const float bb = bg[cl];
            #pragma unroll
            for (int r = 0; r < 4; ++r) {
                int row = q * 4 + r;
                int byte = row * 256 + pcol * 2;
                byte ^= (row & 7) << 4;
                *(unsigned short*)((char*)p_lds + byte) = f2bf(accp[nf][r] + bb);
            }
        }
    }
    __syncthreads();

    // phase 2: out cols = h*64 + nf*16 + li, K = 128 (p_lds)
    {
        f32x4 acco[4] = {};
        #pragma unroll
        for (int ks = 0; ks < 4; ++ks) {
            const int k0 = ks * 32;
            int byte = li * 256 + (k0 + q * 8) * 2;
            byte ^= (li & 7) << 4;
            bf16x8 a = *(const bf16x8*)((const char*)p_lds + byte);
            #pragma unroll
            for (int nf = 0; nf < 4; ++nf) {
                const int colblk = 8 + h * 4 + nf;             // Wout starts at col 128
                bf16x8 bfr = *(const bf16x8*)(Wpk2 + (size_t)(colblk * 4 + ks) * 512 + lane16);
                acco[nf] = __builtin_amdgcn_mfma_f32_16x16x32_bf16(a, bfr, acco[nf], 0, 0, 0);
            }
        }
        #pragma unroll
        for (int nf = 0; nf < 4; ++nf) {
            const int col = h * 64 + nf * 16 + li;
            const float bb = bout[col];
            #pragma unroll
            for (int r = 0; r < 4; ++r) {
                const int row = q * 4 + r;
                out[(size_t)(b * T_SEQ + t0 + row) * DMODEL + col] = acco[nf][r] + bb;
            }
        }
    }
}

extern "C" void kernel_launch(void* const* d_in, const int* in_sizes, int n_in,
                              void* d_out, int out_size, void* d_ws, size_t ws_size,
                              hipStream_t stream) {
    const float* H    = (const float*)d_in[0];
    const float* WQ   = (const float*)d_in[1];
    const float* WK   = (const float*)d_in[2];
    const float* WV   = (const float*)d_in[3];
    const float* wq   = (const float*)d_in[4];
    const float* wk   = (const float*)d_in[5];
    const float* wv   = (const float*)d_in[6];
    const float* Wg0  = (const float*)d_in[7];
    const float* bg0  = (const float*)d_in[8];
    const float* Wg1  = (const float*)d_in[9];
    const float* bg1  = (const float*)d_in[10];
    const float* Wout = (const float*)d_in[11];
    const float* bout = (const float*)d_in[12];
    float* out = (float*)d_out;

    char* ws = (char*)d_ws;
    unsigned short* Wallb = (unsigned short*)ws;                  //   294,912 B
    unsigned short* Qb    = (unsigned short*)(ws + 524288);       // 4,194,304 B
    unsigned short* Kpad  = (unsigned short*)(ws + 4718592);      //     2,048 B
    unsigned short* Kb    = (unsigned short*)(ws + 4720640);      // 1,048,576 B
    unsigned short* Vpad  = (unsigned short*)(ws + 5769216);      //     2,048 B
    unsigned short* Vb    = (unsigned short*)(ws + 5771264);      // 1,048,576 B

    conv_w_kernel<<<73, 256, 0, stream>>>(WQ, WK, WV, Wg0, Wg1, Wout, Wallb, Kpad, Vpad);
    qkv_mfma_kernel<<<256, 384, 0, stream>>>(H, Wallb, wq, wk, wv, Qb, Kb, Vb);
    attn_out_kernel<<<B_SZ * T_SEQ / 16, 256, 0, stream>>>(Qb, Kb, Vb, Wallb, bg0, bg1, bout, out);
}

// Round 8
// 28.521 us; speedup vs baseline: 5.5122x; 1.0727x over previous
//
#include <hip/hip_runtime.h>
#include <math.h>

#define T_SEQ 2048
#define DMODEL 256
#define C_HEAD 64
#define NH 4
#define NWIN 16
#define B_SZ 4

typedef __attribute__((ext_vector_type(8))) short bf16x8;
typedef __attribute__((ext_vector_type(8))) unsigned short ushort8;
typedef __attribute__((ext_vector_type(4))) float f32x4;

static __device__ __forceinline__ unsigned short f2bf(float f) {
    union { float f; unsigned int u; } v; v.f = f;
    unsigned int r = v.u + 0x7FFFu + ((v.u >> 16) & 1u);
    return (unsigned short)(r >> 16);
}

// ---------------- conv_w: pack weights fragment-major + rope table ------
// Region 1 (K=256): cols [WQ(256) WK(64) WV(64)]; Region 2 (K=128):
// cols [Wg0(64) Wg1(64) Wout(256)] at +98304. Fragment-major so every
// MFMA B-load is base + lane*16B (coalesced).
// blocks 72..135: rope table rtab[t][k] = (cos, sin)(t * 10000^(-k/8)).
__global__ __launch_bounds__(256) void conv_w_kernel(
    const float* __restrict__ WQ, const float* __restrict__ WK,
    const float* __restrict__ WV, const float* __restrict__ Wg0,
    const float* __restrict__ Wg1, const float* __restrict__ Wout,
    unsigned short* __restrict__ dst, float2* __restrict__ rtab) {
    const int tid = threadIdx.x;
    if (blockIdx.x >= 72) {
        const int idx = (blockIdx.x - 72) * 256 + tid;   // 0..16383
        const int t = idx >> 3, k = idx & 7;
        const float theta = powf(10000.0f, -0.125f * (float)k);
        const float fr = (float)t * theta;
        rtab[idx] = make_float2(cosf(fr), sinf(fr));
        return;
    }
    const int i = blockIdx.x * 256 + tid;               // 18432 vec8
    const float* s; long off; long doff;
    if (i < 12288) {                                    // K=256 region
        const long e = (long)i * 8;
        const int col = (int)(e >> 8), k = (int)(e & 255);
        if      (col < 256) { s = WQ; off = (long)col * 256 + k; }
        else if (col < 320) { s = WK; off = (long)(col - 256) * 256 + k; }
        else                { s = WV; off = (long)(col - 320) * 256 + k; }
        doff = ((long)(col >> 4) * 8 + (k >> 5)) * 512 + ((k >> 3) & 3) * 128 + (col & 15) * 8;
    } else {                                            // K=128 region
        const long e = (long)(i - 12288) * 8;
        const int col = (int)(e >> 7), k = (int)(e & 127);
        if      (col < 64)  { s = Wg0; off = (long)col * 128 + k; }
        else if (col < 128) { s = Wg1; off = (long)(col - 64) * 128 + k; }
        else                { s = Wout; off = (long)(col - 128) * 128 + k; }
        doff = 98304 + ((long)(col >> 4) * 4 + (k >> 5)) * 512 + ((k >> 3) & 3) * 128 + (col & 15) * 8;
    }
    const float4* s4 = (const float4*)(s + off);
    float4 a = s4[0], b = s4[1];
    ushort8 o;
    o[0] = f2bf(a.x); o[1] = f2bf(a.y); o[2] = f2bf(a.z); o[3] = f2bf(a.w);
    o[4] = f2bf(b.x); o[5] = f2bf(b.y); o[6] = f2bf(b.z); o[7] = f2bf(b.w);
    *(ushort8*)(dst + doff) = o;
}

// ---------------- fully fused kernel ------------------------------------
// grid = B*(T/16) = 512 blocks, 256 thr (4 waves). Wave h:
//   QKV GEMM: Q head h for rows t0..t0+15  AND  (h<2 ? K : V) for row-half
//   (h&1) of [t0-16, t0+16). RMSNorm + RoPE(table) -> Q/K/V in LDS.
//   Then: S^T = mfma(K,Q), softmax, P relayout, PV, inverse RoPE,
//   gates (K=128), out projection (K=128). One kernel, zero HBM intermediates.
__global__ __launch_bounds__(256) void fused_kernel(
    const float* __restrict__ H, const unsigned short* __restrict__ Wallb,
    const float* __restrict__ wq, const float* __restrict__ wk,
    const float* __restrict__ wv, const float2* __restrict__ rtab,
    const float* __restrict__ bg0, const float* __restrict__ bg1,
    const float* __restrict__ bout, float* __restrict__ out)
{
    __shared__ __align__(16) unsigned short lds_a[32 * 256];   // 16KB H tile
    __shared__ __align__(16) unsigned short q_lds[4][16 * 64]; // 8KB
    __shared__ __align__(16) unsigned short k_lds[32 * 64];    // 4KB
    __shared__ __align__(16) unsigned short v_lds[4 * 512];    // 4KB ctile layout
    __shared__ __align__(16) char p_att[4 * 1024];             // 4KB
    __shared__ __align__(16) unsigned short o_lds[16 * 256];   // 8KB
    __shared__ __align__(16) unsigned short p_lds[16 * 128];   // 4KB
    const int tid = threadIdx.x;
    const int blk = blockIdx.x;
    const int b  = blk >> 7;
    const int t0 = (blk & 127) << 4;

    const unsigned short* Wpk2 = Wallb + 98304;   // K=128 packed region

    // ---- stage H rows [t0-16, t0+16) (clamped), f32 -> bf16, swizzled ----
    {
        for (int idx = tid; idx < 1024; idx += 256) {
            int row = idx >> 5, ch = idx & 31;
            int t = t0 - 16 + row; if (t < 0) t = 0;   // masked later
            const float4* s4 = (const float4*)(H + ((size_t)b * T_SEQ + t) * DMODEL + ch * 8);
            float4 a = s4[0], c = s4[1];
            ushort8 o;
            o[0] = f2bf(a.x); o[1] = f2bf(a.y); o[2] = f2bf(a.z); o[3] = f2bf(a.w);
            o[4] = f2bf(c.x); o[5] = f2bf(c.y); o[6] = f2bf(c.z); o[7] = f2bf(c.w);
            int byte = row * 512 + ch * 16;
            byte ^= (row & 7) << 4;
            *(ushort8*)((char*)lds_a + byte) = o;
        }
    }
    __syncthreads();

    const int h  = tid >> 6;
    const int l  = tid & 63;
    const int g  = l >> 4;
    const int li = l & 15;
    const int lane16 = l * 8;      // packed-W per-lane elem offset (16B/lane)

    // ---- QKV MFMAs: Q head h (staged rows 16..31) + K/V half ------------
    const int sel = h >> 1;        // 0 = K, 1 = V
    const int mfh = h & 1;         // row half of the 32-row K/V tile
    f32x4 accq[4] = {};
    f32x4 acckv[4] = {};
    #pragma unroll
    for (int ks = 0; ks < 8; ++ks) {
        const int rowq = 16 + li;
        int byteq = rowq * 512 + (ks * 32 + g * 8) * 2;
        byteq ^= (rowq & 7) << 4;
        bf16x8 aq = *(const bf16x8*)((const char*)lds_a + byteq);
        const int rowk = mfh * 16 + li;
        int bytek = rowk * 512 + (ks * 32 + g * 8) * 2;
        bytek ^= (rowk & 7) << 4;
        bf16x8 akv = *(const bf16x8*)((const char*)lds_a + bytek);
        #pragma unroll
        for (int nf = 0; nf < 4; ++nf) {
            bf16x8 bq = *(const bf16x8*)(Wallb + (size_t)((h * 4 + nf) * 8 + ks) * 512 + lane16);
            accq[nf] = __builtin_amdgcn_mfma_f32_16x16x32_bf16(aq, bq, accq[nf], 0, 0, 0);
            bf16x8 bkv = *(const bf16x8*)(Wallb + (size_t)((16 + sel * 4 + nf) * 8 + ks) * 512 + lane16);
            acckv[nf] = __builtin_amdgcn_mfma_f32_16x16x32_bf16(akv, bkv, acckv[nf], 0, 0, 0);
        }
    }

    // ---- Q epilogue: rmsnorm + rope -> q_lds[h] --------------------------
    {
        float gw[4];
        #pragma unroll
        for (int nf = 0; nf < 4; ++nf) gw[nf] = wq[h * 64 + nf * 16 + li];
        #pragma unroll
        for (int r = 0; r < 4; ++r) {
            float x0 = accq[0][r], x1 = accq[1][r];
            float x2 = accq[2][r], x3 = accq[3][r];
            float ss = x0 * x0 + x1 * x1 + x2 * x2 + x3 * x3;
            ss += __shfl_xor(ss, 1);
            ss += __shfl_xor(ss, 2);
            ss += __shfl_xor(ss, 4);
            ss += __shfl_xor(ss, 8);
            const float rinv = rsqrtf(ss * (1.0f / 64.0f) + 1e-8f);
            const int tok = g * 4 + r;
            const int t = t0 + tok;
            float v0 = x0 * rinv * gw[0];
            float v1 = x1 * rinv * gw[1];
            float v2 = x2 * rinv * gw[2];
            float v3 = x3 * rinv * gw[3];
            float2 cs = rtab[t * 8 + (li >> 1)];
            float px = __shfl_xor(v3, 1);
            v3 = ((li & 1) == 0) ? (v3 * cs.x - px * cs.y) : (px * cs.y + v3 * cs.x);
            char* qb = (char*)q_lds[h];
            const int sw = (tok & 7) << 4;
            *(unsigned short*)(qb + ((tok * 128 + (0 * 16 + li) * 2) ^ sw)) = f2bf(v0);
            *(unsigned short*)(qb + ((tok * 128 + (1 * 16 + li) * 2) ^ sw)) = f2bf(v1);
            *(unsigned short*)(qb + ((tok * 128 + (2 * 16 + li) * 2) ^ sw)) = f2bf(v2);
            *(unsigned short*)(qb + ((tok * 128 + (3 * 16 + li) * 2) ^ sw)) = f2bf(v3);
        }
    }

    // ---- K/V epilogue: rmsnorm + rope -> k_lds / v_lds -------------------
    {
        float gw[4];
        #pragma unroll
        for (int nf = 0; nf < 4; ++nf)
            gw[nf] = (sel == 0) ? wk[nf * 16 + li] : wv[nf * 16 + li];
        #pragma unroll
        for (int r = 0; r < 4; ++r) {
            float x0 = acckv[0][r], x1 = acckv[1][r];
            float x2 = acckv[2][r], x3 = acckv[3][r];
            float ss = x0 * x0 + x1 * x1 + x2 * x2 + x3 * x3;
            ss += __shfl_xor(ss, 1);
            ss += __shfl_xor(ss, 2);
            ss += __shfl_xor(ss, 4);
            ss += __shfl_xor(ss, 8);
            const float rinv = rsqrtf(ss * (1.0f / 64.0f) + 1e-8f);
            const int row = mfh * 16 + g * 4 + r;     // staged row 0..31
            int tk = t0 - 16 + row; if (tk < 0) tk = 0;  // masked anyway
            float v0 = x0 * rinv * gw[0];
            float v1 = x1 * rinv * gw[1];
            float v2 = x2 * rinv * gw[2];
            float v3 = x3 * rinv * gw[3];
            float2 cs = rtab[tk * 8 + (li >> 1)];
            float px = __shfl_xor(v3, 1);
            v3 = ((li & 1) == 0) ? (v3 * cs.x - px * cs.y) : (px * cs.y + v3 * cs.x);
            if (sel == 0) {
                char* kb = (char*)k_lds;
                const int sw = (row & 7) << 4;
                *(unsigned short*)(kb + ((row * 128 + (0 * 16 + li) * 2) ^ sw)) = f2bf(v0);
                *(unsigned short*)(kb + ((row * 128 + (1 * 16 + li) * 2) ^ sw)) = f2bf(v1);
                *(unsigned short*)(kb + ((row * 128 + (2 * 16 + li) * 2) ^ sw)) = f2bf(v2);
                *(unsigned short*)(kb + ((row * 128 + (3 * 16 + li) * 2) ^ sw)) = f2bf(v3);
            } else {
                char* vb = (char*)v_lds;
                const int sw = (row & 12) << 3;
                *(unsigned short*)(vb + ((0 * 1024 + row * 32 + li * 2) ^ sw)) = f2bf(v0);
                *(unsigned short*)(vb + ((1 * 1024 + row * 32 + li * 2) ^ sw)) = f2bf(v1);
                *(unsigned short*)(vb + ((2 * 1024 + row * 32 + li * 2) ^ sw)) = f2bf(v2);
                *(unsigned short*)(vb + ((3 * 1024 + row * 32 + li * 2) ^ sw)) = f2bf(v3);
            }
        }
    }
    __syncthreads();

    // ---- attention: S^T = mfma(K, Q) -------------------------------------
    bf16x8 qf0, qf1;
    {
        const char* qb = (const char*)q_lds[h];
        const int sw = (li & 7) << 4;
        qf0 = *(const bf16x8*)(qb + ((li * 128 + g * 16) ^ sw));
        qf1 = *(const bf16x8*)(qb + ((li * 128 + 64 + g * 16) ^ sw));
    }
    f32x4 st[2];
    #pragma unroll
    for (int tile = 0; tile < 2; ++tile) {
        const int row = tile * 16 + li;
        const char* kb = (const char*)k_lds;
        const int sw = (row & 7) << 4;
        bf16x8 kf0 = *(const bf16x8*)(kb + ((row * 128 + g * 16) ^ sw));
        bf16x8 kf1 = *(const bf16x8*)(kb + ((row * 128 + 64 + g * 16) ^ sw));
        f32x4 acc = {};
        acc = __builtin_amdgcn_mfma_f32_16x16x32_bf16(kf0, qf0, acc, 0, 0, 0);
        acc = __builtin_amdgcn_mfma_f32_16x16x32_bf16(kf1, qf1, acc, 0, 0, 0);
        st[tile] = acc;
    }

    float p[8];
    float mx = -1e30f;
    #pragma unroll
    for (int tile = 0; tile < 2; ++tile) {
        #pragma unroll
        for (int r = 0; r < 4; ++r) {
            int krel = tile * 16 - 16 + g * 4 + r;
            int dd = li - krel;
            bool ok = ((unsigned)dd < 16u) && (t0 + krel >= 0);
            float v = ok ? st[tile][r] * 0.125f : -1e30f;
            p[tile * 4 + r] = v;
            mx = fmaxf(mx, v);
        }
    }
    mx = fmaxf(mx, __shfl_xor(mx, 16));
    mx = fmaxf(mx, __shfl_xor(mx, 32));
    float sum = 0.f;
    #pragma unroll
    for (int i = 0; i < 8; ++i) { p[i] = __expf(p[i] - mx); sum += p[i]; }
    sum += __shfl_xor(sum, 16);
    sum += __shfl_xor(sum, 32);
    const float inv = 1.0f / sum;

    // P -> wave-local LDS relayout to K=32 A-fragment
    bf16x8 paf;
    {
        char* pbase = p_att + h * 1024;
        uint2 w0, w1;
        w0.x = (unsigned)f2bf(p[0] * inv) | ((unsigned)f2bf(p[1] * inv) << 16);
        w0.y = (unsigned)f2bf(p[2] * inv) | ((unsigned)f2bf(p[3] * inv) << 16);
        w1.x = (unsigned)f2bf(p[4] * inv) | ((unsigned)f2bf(p[5] * inv) << 16);
        w1.y = (unsigned)f2bf(p[6] * inv) | ((unsigned)f2bf(p[7] * inv) << 16);
        const int sw = (li & 3) << 4;
        *(uint2*)(pbase + ((li * 64 + 0 * 32 + g * 8) ^ sw)) = w0;
        *(uint2*)(pbase + ((li * 64 + 1 * 32 + g * 8) ^ sw)) = w1;
        asm volatile("s_waitcnt lgkmcnt(0)" ::: "memory");
        paf = *(const bf16x8*)(pbase + ((li * 64 + g * 16) ^ sw));
    }

    // PV: O[16 tok][64 ch]
    f32x4 o[4] = {};
    #pragma unroll
    for (int ctile = 0; ctile < 4; ++ctile) {
        bf16x8 vf;
        #pragma unroll
        for (int j = 0; j < 8; ++j) {
            int key = g * 8 + j;
            int byte = ctile * 1024 + key * 32 + li * 2;
            byte ^= (key & 12) << 3;
            vf[j] = *(const short*)((const char*)v_lds + byte);
        }
        o[ctile] = __builtin_amdgcn_mfma_f32_16x16x32_bf16(paf, vf, o[ctile], 0, 0, 0);
    }

    // inverse rope on chans 48..63 (ctile 3); write O to swizzled LDS
    #pragma unroll
    for (int r = 0; r < 4; ++r) {
        const int t = t0 + g * 4 + r;
        float o3 = o[3][r];
        float po = __shfl_xor(o3, 1);
        float2 cs = rtab[t * 8 + (li >> 1)];
        o3 = ((li & 1) == 0) ? (o3 * cs.x + po * cs.y) : (-po * cs.y + o3 * cs.x);
        const int row = g * 4 + r;
        #pragma unroll
        for (int ctile = 0; ctile < 4; ++ctile) {
            const int col = h * 64 + ctile * 16 + li;
            int byte = row * 512 + col * 2;
            byte ^= (row & 7) << 4;
            float val = (ctile == 3) ? o3 : o[ctile][r];
            *(unsigned short*)((char*)o_lds + byte) = f2bf(val);
        }
    }
    __syncthreads();

    // phase 1: gates. wave h: gate=h>>1, half=h&1
    const int gate = h >> 1, half = h & 1;
    const float* bg = gate ? bg1 : bg0;
    {
        f32x4 accp[2] = {};
        #pragma unroll
        for (int ks = 0; ks < 4; ++ks) {
            const int k0 = ks * 32;
            int byte = li * 512 + (gate * 128 + k0 + g * 8) * 2;
            byte ^= (li & 7) << 4;
            bf16x8 a = *(const bf16x8*)((const char*)o_lds + byte);
            #pragma unroll
            for (int nf = 0; nf < 2; ++nf) {
                const int colblk = gate * 4 + half * 2 + nf;
                bf16x8 bfr = *(const bf16x8*)(Wpk2 + (size_t)(colblk * 4 + ks) * 512 + lane16);
                accp[nf] = __builtin_amdgcn_mfma_f32_16x16x32_bf16(a, bfr, accp[nf], 0, 0, 0);
            }
        }
        #pragma unroll
        for (int nf = 0; nf < 2; ++nf) {
            const int cl = half * 32 + nf * 16 + li;
            const int pcol = gate * 64 + cl;
            const float bb = bg[cl];
            #pragma unroll
            for (int r = 0; r < 4; ++r) {
                int row = g * 4 + r;
                int byte = row * 256 + pcol * 2;
                byte ^= (row & 7) << 4;
                *(unsigned short*)((char*)p_lds + byte) = f2bf(accp[nf][r] + bb);
            }
        }
    }
    __syncthreads();

    // phase 2: out cols = h*64 + nf*16 + li, K = 128 (p_lds)
    {
        f32x4 acco[4] = {};
        #pragma unroll
        for (int ks = 0; ks < 4; ++ks) {
            const int k0 = ks * 32;
            int byte = li * 256 + (k0 + g * 8) * 2;
            byte ^= (li & 7) << 4;
            bf16x8 a = *(const bf16x8*)((const char*)p_lds + byte);
            #pragma unroll
            for (int nf = 0; nf < 4; ++nf) {
                const int colblk = 8 + h * 4 + nf;             // Wout at col 128
                bf16x8 bfr = *(const bf16x8*)(Wpk2 + (size_t)(colblk * 4 + ks) * 512 + lane16);
                acco[nf] = __builtin_amdgcn_mfma_f32_16x16x32_bf16(a, bfr, acco[nf], 0, 0, 0);
            }
        }
        #pragma unroll
        for (int nf = 0; nf < 4; ++nf) {
            const int col = h * 64 + nf * 16 + li;
            const float bb = bout[col];
            #pragma unroll
            for (int r = 0; r < 4; ++r) {
                const int row = g * 4 + r;
                out[(size_t)(b * T_SEQ + t0 + row) * DMODEL + col] = acco[nf][r] + bb;
            }
        }
    }
}

extern "C" void kernel_launch(void* const* d_in, const int* in_sizes, int n_in,
                              void* d_out, int out_size, void* d_ws, size_t ws_size,
                              hipStream_t stream) {
    const float* H    = (const float*)d_in[0];
    const float* WQ   = (const float*)d_in[1];
    const float* WK   = (const float*)d_in[2];
    const float* WV   = (const float*)d_in[3];
    const float* wq   = (const float*)d_in[4];
    const float* wk   = (const float*)d_in[5];
    const float* wv   = (const float*)d_in[6];
    const float* Wg0  = (const float*)d_in[7];
    const float* bg0  = (const float*)d_in[8];
    const float* Wg1  = (const float*)d_in[9];
    const float* bg1  = (const float*)d_in[10];
    const float* Wout = (const float*)d_in[11];
    const float* bout = (const float*)d_in[12];
    float* out = (float*)d_out;

    char* ws = (char*)d_ws;
    unsigned short* Wallb = (unsigned short*)ws;          // 294,912 B
    float2* rtab = (float2*)(ws + 294912);                // 131,072 B

    conv_w_kernel<<<136, 256, 0, stream>>>(WQ, WK, WV, Wg0, Wg1, Wout, Wallb, rtab);
    fused_kernel<<<B_SZ * T_SEQ / 16, 256, 0, stream>>>(H, Wallb, wq, wk, wv, rtab,
                                                        bg0, bg1, bout, out);
}